// Round 11
// baseline (5341.742 us; speedup 1.0000x reference)
//
#include <hip/hip_runtime.h>
#include <math.h>

// Problem constants: B=8, S=224, P=14, D=512, L=6, NPS=16, N=256, G=5, H=2048, iters=12
#define L6 6

typedef __attribute__((ext_vector_type(8))) short bf16x8;   // 8 bf16 in 4 VGPRs
typedef __attribute__((ext_vector_type(4))) float f32x4;    // MFMA accum

#define SH_W_GRP   2097152ull   // 512*2048 hi/lo bf16 (both W1 and W2)
#define SH_A_GRP   2097152ull   // 2048 tok * 512 d hi/lo
#define SH_A_TDOFF 10485760ull  // Atd offset inside Apk (5 groups)

// Exact gelu (erff): r10-proven epilogue.
__device__ __forceinline__ float gelu_exact(float x) {
  return 0.5f * x * (1.0f + erff(x * 0.70710678118654752f));
}

__device__ __forceinline__ unsigned short bf16_rn(float x) {
  unsigned u = __float_as_uint(x);
  unsigned r = u + 0x7FFFu + ((u >> 16) & 1u);
  return (unsigned short)(r >> 16);
}
__device__ __forceinline__ float bf16_f(unsigned short h) {
  return __uint_as_float(((unsigned)h) << 16);
}
__device__ __forceinline__ void split2(float x, unsigned short* h, unsigned short* l) {
  unsigned short hh = bf16_rn(x);
  *h = hh;
  *l = bf16_rn(x - bf16_f(hh));
}
__device__ __forceinline__ int4 pack8(const unsigned short* v) {
  return make_int4((int)((unsigned)v[0] | ((unsigned)v[1] << 16)),
                   (int)((unsigned)v[2] | ((unsigned)v[3] << 16)),
                   (int)((unsigned)v[4] | ((unsigned)v[5] << 16)),
                   (int)((unsigned)v[6] | ((unsigned)v[7] << 16)));
}

__device__ __forceinline__ void gload16(const void* g, void* l) {
  __builtin_amdgcn_global_load_lds(
      (const __attribute__((address_space(1))) void*)g,
      (__attribute__((address_space(3))) void*)l, 16, 0, 0);
}

// ---------------------------------------------------------------------------
// Patch embedding
// ---------------------------------------------------------------------------
__global__ __launch_bounds__(256) void patch_embed(
    const float* __restrict__ img, const float* __restrict__ Wp,
    const float* __restrict__ bp, float* __restrict__ tokens)
{
  __shared__ float xs[588];
  const int bn = blockIdx.x;
  const int b = bn >> 8, n = bn & 255;
  const int i = n >> 4, j = n & 15;
  for (int k = threadIdx.x; k < 588; k += 256) {
    int c = k % 3;
    int t = k / 3;
    int pc = t % 14;
    int pr = t / 14;
    xs[k] = img[(((size_t)(b * 3 + c) * 224) + (i * 14 + pr)) * 224 + (j * 14 + pc)];
  }
  __syncthreads();
  const int d0 = threadIdx.x, d1 = threadIdx.x + 256;
  float a0 = 0.f, a1 = 0.f;
  for (int k = 0; k < 588; ++k) {
    float x = xs[k];
    a0 = fmaf(x, Wp[(size_t)k * 512 + d0], a0);
    a1 = fmaf(x, Wp[(size_t)k * 512 + d1], a1);
  }
  tokens[(size_t)bn * 512 + d0] = a0 + bp[d0];
  tokens[(size_t)bn * 512 + d1] = a1 + bp[d1];
}

// ---------------------------------------------------------------------------
__global__ __launch_bounds__(256) void init_lv_kernel(
    const float* __restrict__ initl, float* __restrict__ lv)
{
  int f = blockIdx.x * 256 + threadIdx.x;
  int d4 = f & 127;
  int l = (f >> 15) % 6;
  float4 v = *(const float4*)(initl + (size_t)l * 512 + d4 * 4);
  *(float4*)(lv + (size_t)f * 4) = v;
}

// ---------------------------------------------------------------------------
// Startup norms: invn[bl][n] = 1/max(||lv[bl,n,:]||, 1e-12). One-shot;
// steady-state values produced by combine3's fused wave-reduce.
// ---------------------------------------------------------------------------
__global__ __launch_bounds__(256) void norm0_k(
    const float* __restrict__ lv, float* __restrict__ invn)
{
  int bl = blockIdx.x;
  int n = threadIdx.x;
  const float* row = lv + ((size_t)bl * 256 + n) * 512;
  float ss = 0.f;
  for (int k = 0; k < 512; k += 4) {
    float4 v = *(const float4*)(row + k);
    ss = fmaf(v.x, v.x, ss);
    ss = fmaf(v.y, v.y, ss);
    ss = fmaf(v.z, v.z, ss);
    ss = fmaf(v.w, v.w, ss);
  }
  invn[(size_t)bl * 256 + n] = 1.0f / fmaxf(sqrtf(ss), 1e-12f);
}

// ---------------------------------------------------------------------------
// Pack weights fp32 [G][K][N] -> hi/lo bf16 fragment-image.
// ---------------------------------------------------------------------------
__global__ __launch_bounds__(256) void pack_w(
    const float* __restrict__ src, short* __restrict__ dst, int KT, int NT)
{
  int sidx = blockIdx.x * 256 + threadIdx.x;
  int slot = sidx & 511;
  int blk = sidx >> 9;
  int kt = blk % KT;
  int rest = blk / KT;
  int nt = rest % NT;
  int g = rest / NT;
  int f = slot >> 6, lane = slot & 63;
  int N = NT * 128, K = KT * 32;
  int n = nt * 128 + f * 16 + (lane & 15);
  int k0 = kt * 32 + (lane >> 4) * 8;
  const float* s = src + ((size_t)g * K + k0) * N + n;
  unsigned short hi[8], lo[8];
#pragma unroll
  for (int j = 0; j < 8; ++j) split2(s[(size_t)j * N], &hi[j], &lo[j]);
  short* d = dst + (size_t)blk * 8192 + slot * 8;
  *(int4*)d = pack8(hi);
  *(int4*)(d + 4096) = pack8(lo);
}

// ---------------------------------------------------------------------------
// Startup A-pack (steady-state fused into combine3).
// ---------------------------------------------------------------------------
__global__ __launch_bounds__(256) void pack_A(
    const float* __restrict__ lv, const float* __restrict__ pos,
    short* __restrict__ Abu, short* __restrict__ Atd)
{
  const int bx = blockIdx.x;              // 0..1279
  const int lg = bx >> 8, mt = (bx >> 4) & 15, kt = bx & 15;
  const size_t blk = (size_t)bx * 8192;
#pragma unroll
  for (int ss = 0; ss < 2; ++ss) {
    int s = threadIdx.x + ss * 256;
    int f = s >> 6, l = s & 63;
    int m = mt * 128 + (f << 4) + (l & 15);
    int b = m >> 8, n = m & 255;
    int d = kt * 32 + ((l >> 4) << 3);
    const float* pbu = lv + ((size_t)(b * L6 + lg) * 256 + n) * 512 + d;
    const float* ptd = lv + ((size_t)(b * L6 + lg + 1) * 256 + n) * 512 + d;
    const float* pp = pos + (size_t)n * 512 + d;
    float4 u0 = *(const float4*)pbu;
    float4 u1 = *(const float4*)(pbu + 4);
    float xv[8] = {u0.x, u0.y, u0.z, u0.w, u1.x, u1.y, u1.z, u1.w};
    unsigned short hi[8], lo[8];
#pragma unroll
    for (int j = 0; j < 8; ++j) split2(xv[j], &hi[j], &lo[j]);
    *(int4*)(Abu + blk + s * 8) = pack8(hi);
    *(int4*)(Abu + blk + 4096 + s * 8) = pack8(lo);
    float4 v0 = *(const float4*)ptd;
    float4 v1 = *(const float4*)(ptd + 4);
    float4 p0 = *(const float4*)pp;
    float4 p1 = *(const float4*)(pp + 4);
    float yv[8] = {v0.x + p0.x, v0.y + p0.y, v0.z + p0.z, v0.w + p0.w,
                   v1.x + p1.x, v1.y + p1.y, v1.z + p1.z, v1.w + p1.w};
#pragma unroll
    for (int j = 0; j < 8; ++j) split2(yv[j], &hi[j], &lo[j]);
    *(int4*)(Atd + blk + s * 8) = pack8(hi);
    *(int4*)(Atd + blk + 4096 + s * 8) = pack8(lo);
  }
}

// ---------------------------------------------------------------------------
// FF1 r11: flat GEMM, 32x32 wave tiles, grid 5120 (was 64x64 / 1280).
// ff1 was grid-limited at 20 waves/CU (5120 waves) with VGPR=64/LDS=0 —
// HW can host 32. 32x32 tiles quadruple wave count (20480 -> 32/CU capped)
// and shrink the per-wave step to {8 loads, 12 MFMA} for finer interleave.
// launch_bounds(256,8) caps VGPR at 64 (acc16+A16+B16+addr fits; compiler
// historically compresses to 64 anyway). r10's explicit SW pipeline was
// compiler-defeated (VGPR stayed 64) — scheduling axis closed; this is the
// TLP axis. Same fragment values + per-acc MFMA order -> bit-identical.
// ---------------------------------------------------------------------------
__global__ __launch_bounds__(256, 8) void ff1_k(
    const short* __restrict__ Wa, const short* __restrict__ Ap,
    const float* __restrict__ b1, short* __restrict__ hpk)
{
  const int per_x = gridDim.x >> 3;            // 640
  const int gid = (blockIdx.x & 7) * per_x + (blockIdx.x >> 3);
  const int tt6 = gid & 31;                    // 32 token-tiles of 64
  const int ht6 = (gid >> 5) & 31;             // 32 H-tiles of 64
  const int z = gid >> 10;                     // 0..4
  const int tid = threadIdx.x, lane = tid & 63, w = tid >> 6;
  const int H0 = ht6 * 64 + (w >> 1) * 32;     // this wave's H base
  const int T0 = tt6 * 64 + (w & 1) * 32;      // this wave's token base
  const short* ga = Wa + (size_t)(z * 16 + (H0 >> 7)) * 16 * 8192
                    + (H0 & 127) * 32 + lane * 8;
  const short* gb = Ap + (size_t)(z * 16 + (T0 >> 7)) * 16 * 8192
                    + (T0 & 127) * 32 + lane * 8;

  f32x4 acc[2][2];
#pragma unroll
  for (int i = 0; i < 2; ++i)
#pragma unroll
    for (int j = 0; j < 2; ++j) acc[i][j] = (f32x4)(0.0f);

  for (int kt = 0; kt < 16; ++kt) {
    const short* pa = ga + (size_t)kt * 8192;
    const short* pb = gb + (size_t)kt * 8192;
    bf16x8 ah[2], al[2], bh[2], bl[2];
#pragma unroll
    for (int i = 0; i < 2; ++i) {
      ah[i] = *(const bf16x8*)(pa + i * 512);
      al[i] = *(const bf16x8*)(pa + 4096 + i * 512);
    }
#pragma unroll
    for (int j = 0; j < 2; ++j) {
      bh[j] = *(const bf16x8*)(pb + j * 512);
      bl[j] = *(const bf16x8*)(pb + 4096 + j * 512);
    }
    // pass 1: A_hi * B_hi
#pragma unroll
    for (int j = 0; j < 2; ++j)
#pragma unroll
      for (int i = 0; i < 2; ++i)
        acc[i][j] = __builtin_amdgcn_mfma_f32_16x16x32_bf16(
            ah[i], bh[j], acc[i][j], 0, 0, 0);
    // pass 2: A_lo * B_hi
#pragma unroll
    for (int j = 0; j < 2; ++j)
#pragma unroll
      for (int i = 0; i < 2; ++i)
        acc[i][j] = __builtin_amdgcn_mfma_f32_16x16x32_bf16(
            al[i], bh[j], acc[i][j], 0, 0, 0);
    // pass 3: A_hi * B_lo
#pragma unroll
    for (int j = 0; j < 2; ++j)
#pragma unroll
      for (int i = 0; i < 2; ++i)
        acc[i][j] = __builtin_amdgcn_mfma_f32_16x16x32_bf16(
            ah[i], bl[j], acc[i][j], 0, 0, 0);
  }

  const int q = lane >> 4, t = lane & 15;
  const float* b1g = b1 + (size_t)z * 2048;
#pragma unroll
  for (int i = 0; i < 2; ++i) {
    int Hb = H0 + i * 16 + q * 4;
    float4 bv = *(const float4*)(b1g + Hb);
    float bb[4] = {bv.x, bv.y, bv.z, bv.w};
    int kt2 = Hb >> 5;
    int g2 = (Hb >> 3) & 3;
    int jb = Hb & 7;                       // 0 or 4
    size_t blkbase = ((size_t)(z * 16 + (T0 >> 7)) * 64 + kt2) * 8192;
#pragma unroll
    for (int j = 0; j < 2; ++j) {
      int f2 = ((T0 & 127) >> 4) + j;
      size_t off = blkbase + (size_t)(f2 * 64 + g2 * 16 + t) * 8 + jb;
      unsigned short hi[4], lo[4];
#pragma unroll
      for (int r = 0; r < 4; ++r) {
        float x = gelu_exact(acc[i][j][r] + bb[r]);
        split2(x, &hi[r], &lo[r]);
      }
      *(uint2*)(hpk + off) =
          make_uint2((unsigned)hi[0] | ((unsigned)hi[1] << 16),
                     (unsigned)hi[2] | ((unsigned)hi[3] << 16));
      *(uint2*)(hpk + off + 4096) =
          make_uint2((unsigned)lo[0] | ((unsigned)lo[1] << 16),
                     (unsigned)lo[2] | ((unsigned)lo[3] << 16));
    }
  }
}

// ---------------------------------------------------------------------------
// Attention r7: MFMA Gram with norm table (best configuration).
// ---------------------------------------------------------------------------
__global__ __launch_bounds__(256, 3) void attn_k(
    const float* __restrict__ lv, const short* __restrict__ Apk,
    const float* __restrict__ invn, float* __restrict__ attnb)
{
  __shared__ __align__(16) short Bhi[8192];   // 16 frags x 64 lanes x 8
  __shared__ __align__(16) short Blo[8192];
  __shared__ float scL[256];
  __shared__ float red[32][4];
  const int a = blockIdx.x;
  const int s = a >> 3;
  const int b = a & 7;                 // batch == XCD group
  const int l = s >> 3;                // level 0..5
  const int bl = b * 6 + l;
  const int i0 = (s & 7) * 32;
  const float* base = lv + (size_t)bl * 131072;
  const int tid = threadIdx.x, lane = tid & 63, w = tid >> 6;
  const int q = lane >> 4, c = lane & 15;

  scL[tid] = invn[(size_t)bl * 256 + tid];   // one row scale per thread

  f32x4 acc[2][4];
#pragma unroll
  for (int i = 0; i < 2; ++i)
#pragma unroll
    for (int j = 0; j < 4; ++j) acc[i][j] = (f32x4)(0.0f);

  // Apk bu-image sub-blocks for this (b,l): tokens n 0..127 -> tile 2b,
  // n 128..255 -> tile 2b+1. Valid only for l<5.
  const short* src0 = Apk + ((size_t)(l * 16 + 2 * b) * 16) * 8192;
  const short* src1 = Apk + ((size_t)(l * 16 + 2 * b + 1) * 16) * 8192;

  for (int kt = 0; kt < 16; ++kt) {
    __syncthreads();                    // prev step's LDS reads done
    if (l < 5) {
      const char* p0 = (const char*)(src0 + (size_t)kt * 8192);
      const char* p1 = (const char*)(src1 + (size_t)kt * 8192);
      gload16(p0 + tid * 16,         (char*)Bhi + tid * 16);
      gload16(p0 + 4096 + tid * 16,  (char*)Bhi + 4096 + tid * 16);
      gload16(p0 + 8192 + tid * 16,  (char*)Blo + tid * 16);
      gload16(p0 + 12288 + tid * 16, (char*)Blo + 4096 + tid * 16);
      gload16(p1 + tid * 16,         (char*)Bhi + 8192 + tid * 16);
      gload16(p1 + 4096 + tid * 16,  (char*)Bhi + 12288 + tid * 16);
      gload16(p1 + 8192 + tid * 16,  (char*)Blo + 8192 + tid * 16);
      gload16(p1 + 12288 + tid * 16, (char*)Blo + 12288 + tid * 16);
    } else {
      const int k0 = kt * 32;
#pragma unroll
      for (int it = 0; it < 8; ++it) {
        int f = it * 256 + tid;
        int j = f >> 3, c4 = f & 7;
        float4 v = *(const float4*)(base + (size_t)j * 512 + k0 + c4 * 4);
        unsigned short hi[4], lo[4];
        split2(v.x, &hi[0], &lo[0]);
        split2(v.y, &hi[1], &lo[1]);
        split2(v.z, &hi[2], &lo[2]);
        split2(v.w, &hi[3], &lo[3]);
        int fg = j >> 4;
        int la = (c4 >> 1) * 16 + (j & 15);
        int half = (c4 & 1) * 4;
        *(uint2*)&Bhi[fg * 512 + la * 8 + half] =
            make_uint2((unsigned)hi[0] | ((unsigned)hi[1] << 16),
                       (unsigned)hi[2] | ((unsigned)hi[3] << 16));
        *(uint2*)&Blo[fg * 512 + la * 8 + half] =
            make_uint2((unsigned)lo[0] | ((unsigned)lo[1] << 16),
                       (unsigned)lo[2] | ((unsigned)lo[3] << 16));
      }
    }
    __syncthreads();                    // staging complete
    bf16x8 ah[2], al[2], bh[4], blv[4];
#pragma unroll
    for (int i = 0; i < 2; ++i) {
      int fg = (i0 >> 4) + i;
      ah[i] = *(const bf16x8*)&Bhi[fg * 512 + lane * 8];
      al[i] = *(const bf16x8*)&Blo[fg * 512 + lane * 8];
    }
#pragma unroll
    for (int j = 0; j < 4; ++j) {
      int fg = w * 4 + j;
      bh[j] = *(const bf16x8*)&Bhi[fg * 512 + lane * 8];
      blv[j] = *(const bf16x8*)&Blo[fg * 512 + lane * 8];
    }
#pragma unroll
    for (int j = 0; j < 4; ++j)
#pragma unroll
      for (int i = 0; i < 2; ++i)
        acc[i][j] = __builtin_amdgcn_mfma_f32_16x16x32_bf16(
            ah[i], bh[j], acc[i][j], 0, 0, 0);
#pragma unroll
    for (int j = 0; j < 4; ++j)
#pragma unroll
      for (int i = 0; i < 2; ++i)
        acc[i][j] = __builtin_amdgcn_mfma_f32_16x16x32_bf16(
            al[i], bh[j], acc[i][j], 0, 0, 0);
#pragma unroll
    for (int j = 0; j < 4; ++j)
#pragma unroll
      for (int i = 0; i < 2; ++i)
        acc[i][j] = __builtin_amdgcn_mfma_f32_16x16x32_bf16(
            ah[i], blv[j], acc[i][j], 0, 0, 0);
  }
  __syncthreads();                      // scL writes visible (also from loop)

  const float rs = 0.04419417382415922f;  // 512^-0.5
  // scale + diag; value at (ai,bj,r): i = i0+ai*16+q*4+r, j = w*64+bj*16+c
#pragma unroll
  for (int ai = 0; ai < 2; ++ai)
#pragma unroll
    for (int bj = 0; bj < 4; ++bj)
#pragma unroll
      for (int r = 0; r < 4; ++r) {
        int i = i0 + ai * 16 + q * 4 + r;
        int j = w * 64 + bj * 16 + c;
        float sv = acc[ai][bj][r] * scL[j] * rs;
        if (j == i) sv = -0.0005f;
        acc[ai][bj][r] = sv;
      }
  // wave-local row max (over this wave's 64 j), then cross-wave via red
  float mx[2][4];
#pragma unroll
  for (int ai = 0; ai < 2; ++ai)
#pragma unroll
    for (int r = 0; r < 4; ++r) {
      float m = fmaxf(fmaxf(acc[ai][0][r], acc[ai][1][r]),
                      fmaxf(acc[ai][2][r], acc[ai][3][r]));
      m = fmaxf(m, __shfl_xor(m, 1));
      m = fmaxf(m, __shfl_xor(m, 2));
      m = fmaxf(m, __shfl_xor(m, 4));
      m = fmaxf(m, __shfl_xor(m, 8));
      mx[ai][r] = m;
    }
  if (c == 0) {
#pragma unroll
    for (int ai = 0; ai < 2; ++ai)
#pragma unroll
      for (int r = 0; r < 4; ++r) red[ai * 16 + q * 4 + r][w] = mx[ai][r];
  }
  __syncthreads();
#pragma unroll
  for (int ai = 0; ai < 2; ++ai)
#pragma unroll
    for (int r = 0; r < 4; ++r) {
      int row = ai * 16 + q * 4 + r;
      mx[ai][r] = fmaxf(fmaxf(red[row][0], red[row][1]),
                        fmaxf(red[row][2], red[row][3]));
    }
  __syncthreads();                      // before red reuse for sums
  float sm[2][4];
#pragma unroll
  for (int ai = 0; ai < 2; ++ai)
#pragma unroll
    for (int r = 0; r < 4; ++r) {
      float t = 0.f;
#pragma unroll
      for (int bj = 0; bj < 4; ++bj) {
        float e = expf(acc[ai][bj][r] - mx[ai][r]);
        acc[ai][bj][r] = e;
        t += e;
      }
      t += __shfl_xor(t, 1);
      t += __shfl_xor(t, 2);
      t += __shfl_xor(t, 4);
      t += __shfl_xor(t, 8);
      sm[ai][r] = t;
    }
  if (c == 0) {
#pragma unroll
    for (int ai = 0; ai < 2; ++ai)
#pragma unroll
      for (int r = 0; r < 4; ++r) red[ai * 16 + q * 4 + r][w] = sm[ai][r];
  }
  __syncthreads();
  float* ob = attnb + (size_t)bl * 65536;
#pragma unroll
  for (int ai = 0; ai < 2; ++ai)
#pragma unroll
    for (int r = 0; r < 4; ++r) {
      int row = ai * 16 + q * 4 + r;
      float S = red[row][0] + red[row][1] + red[row][2] + red[row][3];
      float inv = 1.0f / S;
      int i = i0 + row;
#pragma unroll
      for (int bj = 0; bj < 4; ++bj) {
        int j = w * 64 + bj * 16 + c;
        ob[(size_t)i * 256 + j] = acc[ai][bj][r] * inv;
      }
    }
}

// ---------------------------------------------------------------------------
// Consensus: accum += attnb @ lv (pure RMW). Grid 768, XCD-grouped by bl.
// ---------------------------------------------------------------------------
__global__ __launch_bounds__(256) void cons_k(
    const float* __restrict__ attnb, const float* __restrict__ lv,
    float* __restrict__ accum)
{
  __shared__ __align__(16) char smemraw[25088];
  const int a = blockIdx.x;
  const int s = a >> 3;
  const int bl = (a & 7) * 6 + (s >> 4);
  const int tile = s & 15;
  int it0 = (tile >> 2) * 64;
  int dt0 = (tile & 3) * 128;
  const float* A = attnb + (size_t)bl * 65536;
  const float* Bm = lv + (size_t)bl * 131072;
  float (*Ast)[68] = (float(*)[68])smemraw;
  float (*Bs)[128] = (float(*)[128])(smemraw + 8704);
  const int tid = threadIdx.x;
  const int ty = tid >> 4, tx = tid & 15;
  float acc[4][8];
#pragma unroll
  for (int i = 0; i < 4; ++i)
#pragma unroll
    for (int j = 0; j < 8; ++j) acc[i][j] = 0.f;

  for (int k0 = 0; k0 < 256; k0 += 32) {
#pragma unroll
    for (int it = 0; it < 2; ++it) {
      int f = it * 256 + tid;
      int r = f >> 3, c4 = f & 7;
      float4 v = *(const float4*)(A + (size_t)(it0 + r) * 256 + k0 + c4 * 4);
      Ast[c4 * 4 + 0][r] = v.x;
      Ast[c4 * 4 + 1][r] = v.y;
      Ast[c4 * 4 + 2][r] = v.z;
      Ast[c4 * 4 + 3][r] = v.w;
    }
#pragma unroll
    for (int it = 0; it < 4; ++it) {
      int kr = (tid >> 5) + it * 8;
      int c4 = tid & 31;
      *(float4*)&Bs[kr][c4 * 4] =
          *(const float4*)(Bm + (size_t)(k0 + kr) * 512 + dt0 + c4 * 4);
    }
    __syncthreads();
#pragma unroll 8
    for (int k = 0; k < 32; ++k) {
      float4 av = *(const float4*)&Ast[k][ty * 4];
      float4 b0 = *(const float4*)&Bs[k][tx * 4];
      float4 b1 = *(const float4*)&Bs[k][64 + tx * 4];
      float avv[4] = {av.x, av.y, av.z, av.w};
      float bv[8] = {b0.x, b0.y, b0.z, b0.w, b1.x, b1.y, b1.z, b1.w};
#pragma unroll
      for (int i = 0; i < 4; ++i)
#pragma unroll
        for (int j = 0; j < 8; ++j)
          acc[i][j] = fmaf(avv[i], bv[j], acc[i][j]);
    }
    __syncthreads();
  }
#pragma unroll
  for (int ii = 0; ii < 4; ++ii) {
    int i = it0 + ty * 4 + ii;
    float* arow = accum + (size_t)bl * 131072 + (size_t)i * 512 + dt0;
#pragma unroll
    for (int j = 0; j < 4; ++j) arow[tx * 4 + j] += acc[ii][j];
#pragma unroll
    for (int j = 0; j < 4; ++j) arow[64 + tx * 4 + j] += acc[ii][4 + j];
  }
}

// ---------------------------------------------------------------------------
// FF2: 64(token) x 128(outd) block, 640 blocks, single-buf LDS 24KB.
// r2-proven LDS-staged version. r8's flat conversion REGRESSED (tail 130us):
// the 40MB hpk A-stream thrashes the 4MB/XCD L2, evicting the shared W2
// B-panel. Keep LDS-staged.
//  emode 0 (bu):      accum = lv + v            (store, levels 1..5)
//  emode 1 (td):      l==0: accum=lv+tokens+v;  else accum += v
// ---------------------------------------------------------------------------
__global__ __launch_bounds__(256, 4) void mfma_ff2(
    const short* __restrict__ hpk, const short* __restrict__ Wb,
    const float* __restrict__ b2, const float* __restrict__ lv,
    const float* __restrict__ tokens, float* __restrict__ accum,
    int olvbase, int emode)
{
  const int per_x = gridDim.x >> 3;
  const int gid = (blockIdx.x & 7) * per_x + (blockIdx.x >> 3);
  const int nt2 = gid & 3;
  const int tile = gid >> 2;
  const int mt2 = tile & 31;          // 64-token tiles
  const int z = tile >> 5;

  __shared__ __align__(16) short SA[4096];   // hi 2048 | lo 2048
  __shared__ __align__(16) short SB[8192];   // hi 4096 | lo 4096
  const int tid = threadIdx.x, lane = tid & 63, w = tid >> 6;
  const int wm = (w >> 1) * 32, wn = (w & 1) * 64;
  const short* gaBase = hpk + (size_t)(z * 16 + (mt2 >> 1)) * 64 * 8192
                        + (size_t)(mt2 & 1) * 2048;
  const short* gb = Wb + (size_t)(z * 4 + nt2) * 64 * 8192;

  f32x4 acc[2][4];
#pragma unroll
  for (int i = 0; i < 2; ++i)
#pragma unroll
    for (int j = 0; j < 4; ++j) acc[i][j] = (f32x4)(0.0f);

  for (int kt = 0; kt < 64; ++kt) {
    __syncthreads();
    const char* pa = (const char*)(gaBase + (size_t)kt * 8192);
    const char* pb = (const char*)(gb + (size_t)kt * 8192);
    gload16(pa + w * 1024 + lane * 16, (char*)SA + w * 1024);
    gload16(pa + 8192 + w * 1024 + lane * 16, (char*)SA + 4096 + w * 1024);
#pragma unroll
    for (int c = 0; c < 4; ++c)
      gload16(pb + w * 4096 + c * 1024 + lane * 16,
              (char*)SB + w * 4096 + c * 1024);
    __syncthreads();
    bf16x8 ah[2], al[2];
#pragma unroll
    for (int i = 0; i < 2; ++i) {
      int f = (wm >> 4) + i;
      ah[i] = *(const bf16x8*)&SA[f * 512 + lane * 8];
      al[i] = *(const bf16x8*)&SA[2048 + f * 512 + lane * 8];
    }
#pragma unroll
    for (int jp = 0; jp < 2; ++jp) {
      bf16x8 bh[2], bl[2];
#pragma unroll
      for (int j2 = 0; j2 < 2; ++j2) {
        int f = (wn >> 4) + jp * 2 + j2;
        bh[j2] = *(const bf16x8*)&SB[f * 512 + lane * 8];
        bl[j2] = *(const bf16x8*)&SB[4096 + f * 512 + lane * 8];
      }
#pragma unroll
      for (int j2 = 0; j2 < 2; ++j2)
#pragma unroll
        for (int i = 0; i < 2; ++i)
          acc[i][jp * 2 + j2] = __builtin_amdgcn_mfma_f32_16x16x32_bf16(
              ah[i], bh[j2], acc[i][jp * 2 + j2], 0, 0, 0);
#pragma unroll
      for (int j2 = 0; j2 < 2; ++j2)
#pragma unroll
        for (int i = 0; i < 2; ++i)
          acc[i][jp * 2 + j2] = __builtin_amdgcn_mfma_f32_16x16x32_bf16(
              al[i], bh[j2], acc[i][jp * 2 + j2], 0, 0, 0);
#pragma unroll
      for (int j2 = 0; j2 < 2; ++j2)
#pragma unroll
        for (int i = 0; i < 2; ++i)
          acc[i][jp * 2 + j2] = __builtin_amdgcn_mfma_f32_16x16x32_bf16(
              ah[i], bl[j2], acc[i][jp * 2 + j2], 0, 0, 0);
    }
  }

  const int q = lane >> 4, t = lane & 15;
  const float* b2g = b2 + (size_t)z * 512;
  const int level = olvbase + z;
#pragma unroll
  for (int i = 0; i < 2; ++i) {
#pragma unroll
    for (int r = 0; r < 4; ++r) {
      int m = mt2 * 64 + wm + i * 16 + q * 4 + r;
      int b = m >> 8, n = m & 255;
      size_t rowoff = ((size_t)(b * L6 + level) * 256 + n) * 512;
      float* arow = accum + rowoff;
      const float* lrow = lv + rowoff;
      const float* trow = tokens + (size_t)m * 512;
#pragma unroll
      for (int j = 0; j < 4; ++j) {
        int col = nt2 * 128 + wn + j * 16 + t;
        float v = acc[i][j][r] + b2g[col];
        if (emode == 0)                       arow[col] = lrow[col] + v;
        else if (level == 0)                  arow[col] = lrow[col] + trow[col] + v;
        else                                  arow[col] += v;
      }
    }
  }
}

// ---------------------------------------------------------------------------
// combine3: lv = accum/contrib, write dout on last iter, fused next-iter
// A-packing, and fused exact-fp32 row-norm via 64-lane butterfly.
// ---------------------------------------------------------------------------
__global__ __launch_bounds__(256) void combine3(
    const float* __restrict__ accum, const float* __restrict__ pos,
    float* __restrict__ lv_out, short* __restrict__ Abu,
    short* __restrict__ Atd, float* __restrict__ invn,
    float* __restrict__ dout, int last)
{
  int t = blockIdx.x * 256 + threadIdx.x;   // 786,432 total
  int d8 = t & 63;
  int n = (t >> 6) & 255;
  int v = t >> 14;                          // b*6 + l, 0..47
  int l = v % 6, b = v / 6;
  int bn = (b << 8) | n;
  size_t idx = ((size_t)v * 256 + n) * 512 + d8 * 8;
  float4 a0 = *(const float4*)(accum + idx);
  float4 a1 = *(const float4*)(accum + idx + 4);
  float sc = (l == 5) ? (1.0f / 3.0f) : 0.25f;
  float r[8];
  r[0] = a0.x * sc; r[1] = a0.y * sc; r[2] = a0.z * sc; r[3] = a0.w * sc;
  r[4] = a1.x * sc; r[5] = a1.y * sc; r[6] = a1.z * sc; r[7] = a1.w * sc;
  *(float4*)(lv_out + idx) = make_float4(r[0], r[1], r[2], r[3]);
  *(float4*)(lv_out + idx + 4) = make_float4(r[4], r[5], r[6], r[7]);
  if (last) {
    float* dp = dout + ((size_t)bn * 6 + l) * 512 + d8 * 8;
    *(float4*)dp = make_float4(r[0], r[1], r[2], r[3]);
    *(float4*)(dp + 4) = make_float4(r[4], r[5], r[6], r[7]);
  }
  // fused row norm: wave == one (v,n) row (d8 = lane)
  {
    float s8 = 0.f;
#pragma unroll
    for (int j = 0; j < 8; ++j) s8 = fmaf(r[j], r[j], s8);
#pragma unroll
    for (int o = 1; o < 64; o <<= 1) s8 += __shfl_xor(s8, o);
    if (d8 == 0) invn[(size_t)v * 256 + n] = 1.0f / fmaxf(sqrtf(s8), 1e-12f);
  }
  int m = bn;
  int mt = m >> 7;
  int kt = d8 >> 2;
  int s = (((m & 127) >> 4) << 6) | (((d8 & 3) << 4) | (m & 15));
  unsigned short hi[8], lo[8];
  if (l < 5) {
    size_t blk = ((size_t)(l * 16 + mt) * 16 + kt) * 8192;
#pragma unroll
    for (int j = 0; j < 8; ++j) split2(r[j], &hi[j], &lo[j]);
    *(int4*)(Abu + blk + s * 8) = pack8(hi);
    *(int4*)(Abu + blk + 4096 + s * 8) = pack8(lo);
  }
  if (l >= 1) {
    const float* pp = pos + (size_t)n * 512 + d8 * 8;
    float4 p0 = *(const float4*)pp;
    float4 p1 = *(const float4*)(pp + 4);
    float y[8] = {r[0] + p0.x, r[1] + p0.y, r[2] + p0.z, r[3] + p0.w,
                  r[4] + p1.x, r[5] + p1.y, r[6] + p1.z, r[7] + p1.w};
    size_t blk = ((size_t)((l - 1) * 16 + mt) * 16 + kt) * 8192;
#pragma unroll
    for (int j = 0; j < 8; ++j) split2(y[j], &hi[j], &lo[j]);
    *(int4*)(Atd + blk + s * 8) = pack8(hi);
    *(int4*)(Atd + blk + 4096 + s * 8) = pack8(lo);
  }
}

// ---------------------------------------------------------------------------
extern "C" void kernel_launch(void* const* d_in, const int* in_sizes, int n_in,
                              void* d_out, int out_size, void* d_ws, size_t ws_size,
                              hipStream_t stream)
{
  const float* img   = (const float*)d_in[0];
  const float* Wp    = (const float*)d_in[1];
  const float* bp    = (const float*)d_in[2];
  const float* pos   = (const float*)d_in[3];
  const float* initl = (const float*)d_in[4];
  const float* buW1  = (const float*)d_in[5];
  const float* bub1  = (const float*)d_in[6];
  const float* buW2  = (const float*)d_in[7];
  const float* bub2  = (const float*)d_in[8];
  const float* tdW1  = (const float*)d_in[9];
  const float* tdb1  = (const float*)d_in[10];
  const float* tdW2  = (const float*)d_in[11];
  const float* tdb2  = (const float*)d_in[12];

  float* ws = (float*)d_ws;
  const size_t LV = (size_t)8 * 6 * 256 * 512;   // 6,291,456 floats
  float* lv     = ws;
  float* tokens = lv + LV;                        // 1,048,576
  float* accum  = tokens + 1048576ull;            // 6,291,456
  short* W1all  = (short*)(accum + LV);           // 20,971,520 shorts
  short* W2all  = W1all + 20971520ull;            // 20,971,520 shorts
  short* Apk    = W2all + 20971520ull;            // 20,971,520 shorts
  short* hall   = Apk + 20971520ull;              // 41,943,040 shorts (5z hi/lo)
  float* invn   = (float*)(hall + 41943040ull);   // 48*256 f32 = 49,152 B
  // total = 264,241,152 + 49,152 = 264,290,304 B == proven capacity

  // attnb aliases hall's upper half (12.6 MB needed, 42 MB available);
  // it lives only between attn_k and cons_k, and hall is rewritten by the
  // NEXT iteration's ff1 passes after cons_k has consumed it.
  float* attnb = (float*)(hall + 20971520ull);
  float* dout  = (float*)d_out;

  pack_w<<<2560, 256, 0, stream>>>(buW1, W1all, 16, 16);
  pack_w<<<2560, 256, 0, stream>>>(tdW1, W1all + 5 * SH_W_GRP, 16, 16);
  pack_w<<<2560, 256, 0, stream>>>(buW2, W2all, 64, 4);
  pack_w<<<2560, 256, 0, stream>>>(tdW2, W2all + 5 * SH_W_GRP, 64, 4);

  patch_embed<<<2048, 256, 0, stream>>>(img, Wp, bp, tokens);
  init_lv_kernel<<<6144, 256, 0, stream>>>(initl, lv);
  norm0_k<<<48, 256, 0, stream>>>(lv, invn);
  pack_A<<<1280, 256, 0, stream>>>(lv, pos, Apk, Apk + SH_A_TDOFF);

  for (int it = 0; it < 12; ++it) {
    // K1: ff1-bu (fills hall) — r11 grid 5120 (32x32 wave tiles)
    ff1_k<<<5120, 256, 0, stream>>>(W1all, Apk, bub1, hall);
    // K2: ff2-bu emode0 (store accum = lv + v, levels 1..5)
    mfma_ff2<<<640, 256, 0, stream>>>(hall, W2all, bub2, lv, tokens, accum, 1, 0);
    // K3: ff1-td (refills hall)
    ff1_k<<<5120, 256, 0, stream>>>(W1all + 5 * SH_W_GRP, Apk + SH_A_TDOFF,
                                    tdb1, hall);
    // K4: ff2-td emode1 (level0 store lv+tokens+v; levels 1..4 RMW)
    mfma_ff2<<<640, 256, 0, stream>>>(hall, W2all + 5 * SH_W_GRP, tdb2, lv,
                                      tokens, accum, 0, 1);
    // K5: MFMA attention (reads Apk bu-image + invn; lv only for level 5)
    attn_k<<<384, 256, 0, stream>>>(lv, Apk, invn, attnb);
    // K6: consensus RMW into accum
    cons_k<<<768, 256, 0, stream>>>(attnb, lv, accum);
    // K7: combine + dout + next-iter A-pack + fused norms
    combine3<<<3072, 256, 0, stream>>>(accum, pos, lv, Apk, Apk + SH_A_TDOFF,
                                       invn, dout, it == 11 ? 1 : 0);
  }
}

// Round 12
// 4163.019 us; speedup vs baseline: 1.2831x; 1.2831x over previous
//
#include <hip/hip_runtime.h>
#include <math.h>

// Problem constants: B=8, S=224, P=14, D=512, L=6, NPS=16, N=256, G=5, H=2048, iters=12
#define L6 6

typedef __attribute__((ext_vector_type(8))) short bf16x8;   // 8 bf16 in 4 VGPRs
typedef __attribute__((ext_vector_type(4))) float f32x4;    // MFMA accum

#define SH_W_GRP   2097152ull   // 512*2048 hi/lo bf16 (both W1 and W2)
#define SH_A_TDOFF 10485760ull  // Atd offset inside Apk (5 groups)

// Exact gelu (erff): r10-proven epilogue.
__device__ __forceinline__ float gelu_exact(float x) {
  return 0.5f * x * (1.0f + erff(x * 0.70710678118654752f));
}

__device__ __forceinline__ unsigned short bf16_rn(float x) {
  unsigned u = __float_as_uint(x);
  unsigned r = u + 0x7FFFu + ((u >> 16) & 1u);
  return (unsigned short)(r >> 16);
}
__device__ __forceinline__ float bf16_f(unsigned short h) {
  return __uint_as_float(((unsigned)h) << 16);
}
__device__ __forceinline__ void split2(float x, unsigned short* h, unsigned short* l) {
  unsigned short hh = bf16_rn(x);
  *h = hh;
  *l = bf16_rn(x - bf16_f(hh));
}
__device__ __forceinline__ int4 pack8(const unsigned short* v) {
  return make_int4((int)((unsigned)v[0] | ((unsigned)v[1] << 16)),
                   (int)((unsigned)v[2] | ((unsigned)v[3] << 16)),
                   (int)((unsigned)v[4] | ((unsigned)v[5] << 16)),
                   (int)((unsigned)v[6] | ((unsigned)v[7] << 16)));
}

__device__ __forceinline__ void gload16(const void* g, void* l) {
  __builtin_amdgcn_global_load_lds(
      (const __attribute__((address_space(1))) void*)g,
      (__attribute__((address_space(3))) void*)l, 16, 0, 0);
}

// ---------------------------------------------------------------------------
// Patch embedding
// ---------------------------------------------------------------------------
__global__ __launch_bounds__(256) void patch_embed(
    const float* __restrict__ img, const float* __restrict__ Wp,
    const float* __restrict__ bp, float* __restrict__ tokens)
{
  __shared__ float xs[588];
  const int bn = blockIdx.x;
  const int b = bn >> 8, n = bn & 255;
  const int i = n >> 4, j = n & 15;
  for (int k = threadIdx.x; k < 588; k += 256) {
    int c = k % 3;
    int t = k / 3;
    int pc = t % 14;
    int pr = t / 14;
    xs[k] = img[(((size_t)(b * 3 + c) * 224) + (i * 14 + pr)) * 224 + (j * 14 + pc)];
  }
  __syncthreads();
  const int d0 = threadIdx.x, d1 = threadIdx.x + 256;
  float a0 = 0.f, a1 = 0.f;
  for (int k = 0; k < 588; ++k) {
    float x = xs[k];
    a0 = fmaf(x, Wp[(size_t)k * 512 + d0], a0);
    a1 = fmaf(x, Wp[(size_t)k * 512 + d1], a1);
  }
  tokens[(size_t)bn * 512 + d0] = a0 + bp[d0];
  tokens[(size_t)bn * 512 + d1] = a1 + bp[d1];
}

// ---------------------------------------------------------------------------
__global__ __launch_bounds__(256) void init_lv_kernel(
    const float* __restrict__ initl, float* __restrict__ lv)
{
  int f = blockIdx.x * 256 + threadIdx.x;
  int d4 = f & 127;
  int l = (f >> 15) % 6;
  float4 v = *(const float4*)(initl + (size_t)l * 512 + d4 * 4);
  *(float4*)(lv + (size_t)f * 4) = v;
}

// ---------------------------------------------------------------------------
// Startup norms: invn[bl][n] = 1/max(||lv[bl,n,:]||, 1e-12). One-shot;
// steady-state values produced by combine3's fused wave-reduce.
// ---------------------------------------------------------------------------
__global__ __launch_bounds__(256) void norm0_k(
    const float* __restrict__ lv, float* __restrict__ invn)
{
  int bl = blockIdx.x;
  int n = threadIdx.x;
  const float* row = lv + ((size_t)bl * 256 + n) * 512;
  float ss = 0.f;
  for (int k = 0; k < 512; k += 4) {
    float4 v = *(const float4*)(row + k);
    ss = fmaf(v.x, v.x, ss);
    ss = fmaf(v.y, v.y, ss);
    ss = fmaf(v.z, v.z, ss);
    ss = fmaf(v.w, v.w, ss);
  }
  invn[(size_t)bl * 256 + n] = 1.0f / fmaxf(sqrtf(ss), 1e-12f);
}

// ---------------------------------------------------------------------------
// Pack weights fp32 [G][K][N] -> hi/lo bf16 fragment-image.
// ---------------------------------------------------------------------------
__global__ __launch_bounds__(256) void pack_w(
    const float* __restrict__ src, short* __restrict__ dst, int KT, int NT)
{
  int sidx = blockIdx.x * 256 + threadIdx.x;
  int slot = sidx & 511;
  int blk = sidx >> 9;
  int kt = blk % KT;
  int rest = blk / KT;
  int nt = rest % NT;
  int g = rest / NT;
  int f = slot >> 6, lane = slot & 63;
  int N = NT * 128, K = KT * 32;
  int n = nt * 128 + f * 16 + (lane & 15);
  int k0 = kt * 32 + (lane >> 4) * 8;
  const float* s = src + ((size_t)g * K + k0) * N + n;
  unsigned short hi[8], lo[8];
#pragma unroll
  for (int j = 0; j < 8; ++j) split2(s[(size_t)j * N], &hi[j], &lo[j]);
  short* d = dst + (size_t)blk * 8192 + slot * 8;
  *(int4*)d = pack8(hi);
  *(int4*)(d + 4096) = pack8(lo);
}

// ---------------------------------------------------------------------------
// Startup A-pack (steady-state fused into combine3).
// ---------------------------------------------------------------------------
__global__ __launch_bounds__(256) void pack_A(
    const float* __restrict__ lv, const float* __restrict__ pos,
    short* __restrict__ Abu, short* __restrict__ Atd)
{
  const int bx = blockIdx.x;              // 0..1279
  const int lg = bx >> 8, mt = (bx >> 4) & 15, kt = bx & 15;
  const size_t blk = (size_t)bx * 8192;
#pragma unroll
  for (int ss = 0; ss < 2; ++ss) {
    int s = threadIdx.x + ss * 256;
    int f = s >> 6, l = s & 63;
    int m = mt * 128 + (f << 4) + (l & 15);
    int b = m >> 8, n = m & 255;
    int d = kt * 32 + ((l >> 4) << 3);
    const float* pbu = lv + ((size_t)(b * L6 + lg) * 256 + n) * 512 + d;
    const float* ptd = lv + ((size_t)(b * L6 + lg + 1) * 256 + n) * 512 + d;
    const float* pp = pos + (size_t)n * 512 + d;
    float4 u0 = *(const float4*)pbu;
    float4 u1 = *(const float4*)(pbu + 4);
    float xv[8] = {u0.x, u0.y, u0.z, u0.w, u1.x, u1.y, u1.z, u1.w};
    unsigned short hi[8], lo[8];
#pragma unroll
    for (int j = 0; j < 8; ++j) split2(xv[j], &hi[j], &lo[j]);
    *(int4*)(Abu + blk + s * 8) = pack8(hi);
    *(int4*)(Abu + blk + 4096 + s * 8) = pack8(lo);
    float4 v0 = *(const float4*)ptd;
    float4 v1 = *(const float4*)(ptd + 4);
    float4 p0 = *(const float4*)pp;
    float4 p1 = *(const float4*)(pp + 4);
    float yv[8] = {v0.x + p0.x, v0.y + p0.y, v0.z + p0.z, v0.w + p0.w,
                   v1.x + p1.x, v1.y + p1.y, v1.z + p1.z, v1.w + p1.w};
#pragma unroll
    for (int j = 0; j < 8; ++j) split2(yv[j], &hi[j], &lo[j]);
    *(int4*)(Atd + blk + s * 8) = pack8(hi);
    *(int4*)(Atd + blk + 4096 + s * 8) = pack8(lo);
  }
}

// ---------------------------------------------------------------------------
// FF1 r12: flat GEMM 64x64 wave tiles (r9-proven ~112us), SINGLE-bf16 h
// output (r12): h-lo dropped — halves WRITE (82->41MB) and ff2's A stream.
// hpk block = 4096 shorts (8 frags hi only), blkbase stride *4096.
// A/B operands keep full hi/lo bf16x2 (unchanged GEMM numerics); only the
// h intermediate is truncated (post-gelu, |h|<~1 -> ~5e-4 sigma per ff2 out).
// r11's 32x32 tiles: occupancy 76% but FETCH 2.4x -> slower. r10 SWP:
// compiler-defeated. Keep plain flat.
// ---------------------------------------------------------------------------
__global__ __launch_bounds__(256, 3) void ff1_k(
    const short* __restrict__ Wa, const short* __restrict__ Ap,
    const float* __restrict__ b1, short* __restrict__ hpk)
{
  const int per_x = gridDim.x >> 3;
  const int gid = (blockIdx.x & 7) * per_x + (blockIdx.x >> 3);
  const int tt = gid & 15;
  const int tile = gid >> 4;
  const int ht = tile & 15;
  const int z = tile >> 4;
  const int tid = threadIdx.x, lane = tid & 63, w = tid >> 6;
  const int wm = (w >> 1) * 64, wn = (w & 1) * 64;
  const short* ga = Wa + (size_t)(z * 16 + ht) * 16 * 8192 + (wm << 5) + lane * 8;
  const short* gb = Ap + (size_t)(z * 16 + tt) * 16 * 8192 + (wn << 5) + lane * 8;

  f32x4 acc[4][4];
#pragma unroll
  for (int i = 0; i < 4; ++i)
#pragma unroll
    for (int j = 0; j < 4; ++j) acc[i][j] = (f32x4)(0.0f);

  for (int kt = 0; kt < 16; ++kt) {
    const short* pa = ga + (size_t)kt * 8192;
    const short* pb = gb + (size_t)kt * 8192;
    bf16x8 ah[4], al[4], bh[4], bl[4];
#pragma unroll
    for (int i = 0; i < 4; ++i) {
      ah[i] = *(const bf16x8*)(pa + i * 512);
      al[i] = *(const bf16x8*)(pa + 4096 + i * 512);
    }
#pragma unroll
    for (int j = 0; j < 4; ++j) {
      bh[j] = *(const bf16x8*)(pb + j * 512);
      bl[j] = *(const bf16x8*)(pb + 4096 + j * 512);
    }
    // pass 1: A_hi * B_hi
#pragma unroll
    for (int j = 0; j < 4; ++j)
#pragma unroll
      for (int i = 0; i < 4; ++i)
        acc[i][j] = __builtin_amdgcn_mfma_f32_16x16x32_bf16(
            ah[i], bh[j], acc[i][j], 0, 0, 0);
    // pass 2: A_lo * B_hi
#pragma unroll
    for (int j = 0; j < 4; ++j)
#pragma unroll
      for (int i = 0; i < 4; ++i)
        acc[i][j] = __builtin_amdgcn_mfma_f32_16x16x32_bf16(
            al[i], bh[j], acc[i][j], 0, 0, 0);
    // pass 3: A_hi * B_lo
#pragma unroll
    for (int j = 0; j < 4; ++j)
#pragma unroll
      for (int i = 0; i < 4; ++i)
        acc[i][j] = __builtin_amdgcn_mfma_f32_16x16x32_bf16(
            ah[i], bl[j], acc[i][j], 0, 0, 0);
  }

  const int q = lane >> 4, t = lane & 15;
  const float* b1g = b1 + (size_t)z * 2048;
#pragma unroll
  for (int i = 0; i < 4; ++i) {
    int Hb = ht * 128 + wm + i * 16 + q * 4;
    float4 bv = *(const float4*)(b1g + Hb);
    float bb[4] = {bv.x, bv.y, bv.z, bv.w};
    int kt2 = Hb >> 5;
    int g2 = (Hb >> 3) & 3;
    int jb = Hb & 7;                       // 0 or 4
    size_t blkbase = ((size_t)(z * 16 + tt) * 64 + kt2) * 4096;
#pragma unroll
    for (int j = 0; j < 4; ++j) {
      int f2 = (wn >> 4) + j;
      size_t off = blkbase + (size_t)(f2 * 64 + g2 * 16 + t) * 8 + jb;
      unsigned short hi[4];
#pragma unroll
      for (int r = 0; r < 4; ++r)
        hi[r] = bf16_rn(gelu_exact(acc[i][j][r] + bb[r]));
      *(uint2*)(hpk + off) =
          make_uint2((unsigned)hi[0] | ((unsigned)hi[1] << 16),
                     (unsigned)hi[2] | ((unsigned)hi[3] << 16));
    }
  }
}

// ---------------------------------------------------------------------------
// Attention r7: MFMA Gram with norm table (best configuration).
// ---------------------------------------------------------------------------
__global__ __launch_bounds__(256, 3) void attn_k(
    const float* __restrict__ lv, const short* __restrict__ Apk,
    const float* __restrict__ invn, float* __restrict__ attnb)
{
  __shared__ __align__(16) short Bhi[8192];   // 16 frags x 64 lanes x 8
  __shared__ __align__(16) short Blo[8192];
  __shared__ float scL[256];
  __shared__ float red[32][4];
  const int a = blockIdx.x;
  const int s = a >> 3;
  const int b = a & 7;                 // batch == XCD group
  const int l = s >> 3;                // level 0..5
  const int bl = b * 6 + l;
  const int i0 = (s & 7) * 32;
  const float* base = lv + (size_t)bl * 131072;
  const int tid = threadIdx.x, lane = tid & 63, w = tid >> 6;
  const int q = lane >> 4, c = lane & 15;

  scL[tid] = invn[(size_t)bl * 256 + tid];   // one row scale per thread

  f32x4 acc[2][4];
#pragma unroll
  for (int i = 0; i < 2; ++i)
#pragma unroll
    for (int j = 0; j < 4; ++j) acc[i][j] = (f32x4)(0.0f);

  // Apk bu-image sub-blocks for this (b,l): tokens n 0..127 -> tile 2b,
  // n 128..255 -> tile 2b+1. Valid only for l<5.
  const short* src0 = Apk + ((size_t)(l * 16 + 2 * b) * 16) * 8192;
  const short* src1 = Apk + ((size_t)(l * 16 + 2 * b + 1) * 16) * 8192;

  for (int kt = 0; kt < 16; ++kt) {
    __syncthreads();                    // prev step's LDS reads done
    if (l < 5) {
      const char* p0 = (const char*)(src0 + (size_t)kt * 8192);
      const char* p1 = (const char*)(src1 + (size_t)kt * 8192);
      gload16(p0 + tid * 16,         (char*)Bhi + tid * 16);
      gload16(p0 + 4096 + tid * 16,  (char*)Bhi + 4096 + tid * 16);
      gload16(p0 + 8192 + tid * 16,  (char*)Blo + tid * 16);
      gload16(p0 + 12288 + tid * 16, (char*)Blo + 4096 + tid * 16);
      gload16(p1 + tid * 16,         (char*)Bhi + 8192 + tid * 16);
      gload16(p1 + 4096 + tid * 16,  (char*)Bhi + 12288 + tid * 16);
      gload16(p1 + 8192 + tid * 16,  (char*)Blo + 8192 + tid * 16);
      gload16(p1 + 12288 + tid * 16, (char*)Blo + 12288 + tid * 16);
    } else {
      const int k0 = kt * 32;
#pragma unroll
      for (int it = 0; it < 8; ++it) {
        int f = it * 256 + tid;
        int j = f >> 3, c4 = f & 7;
        float4 v = *(const float4*)(base + (size_t)j * 512 + k0 + c4 * 4);
        unsigned short hi[4], lo[4];
        split2(v.x, &hi[0], &lo[0]);
        split2(v.y, &hi[1], &lo[1]);
        split2(v.z, &hi[2], &lo[2]);
        split2(v.w, &hi[3], &lo[3]);
        int fg = j >> 4;
        int la = (c4 >> 1) * 16 + (j & 15);
        int half = (c4 & 1) * 4;
        *(uint2*)&Bhi[fg * 512 + la * 8 + half] =
            make_uint2((unsigned)hi[0] | ((unsigned)hi[1] << 16),
                       (unsigned)hi[2] | ((unsigned)hi[3] << 16));
        *(uint2*)&Blo[fg * 512 + la * 8 + half] =
            make_uint2((unsigned)lo[0] | ((unsigned)lo[1] << 16),
                       (unsigned)lo[2] | ((unsigned)lo[3] << 16));
      }
    }
    __syncthreads();                    // staging complete
    bf16x8 ah[2], al[2], bh[4], blv[4];
#pragma unroll
    for (int i = 0; i < 2; ++i) {
      int fg = (i0 >> 4) + i;
      ah[i] = *(const bf16x8*)&Bhi[fg * 512 + lane * 8];
      al[i] = *(const bf16x8*)&Blo[fg * 512 + lane * 8];
    }
#pragma unroll
    for (int j = 0; j < 4; ++j) {
      int fg = w * 4 + j;
      bh[j] = *(const bf16x8*)&Bhi[fg * 512 + lane * 8];
      blv[j] = *(const bf16x8*)&Blo[fg * 512 + lane * 8];
    }
#pragma unroll
    for (int j = 0; j < 4; ++j)
#pragma unroll
      for (int i = 0; i < 2; ++i)
        acc[i][j] = __builtin_amdgcn_mfma_f32_16x16x32_bf16(
            ah[i], bh[j], acc[i][j], 0, 0, 0);
#pragma unroll
    for (int j = 0; j < 4; ++j)
#pragma unroll
      for (int i = 0; i < 2; ++i)
        acc[i][j] = __builtin_amdgcn_mfma_f32_16x16x32_bf16(
            al[i], bh[j], acc[i][j], 0, 0, 0);
#pragma unroll
    for (int j = 0; j < 4; ++j)
#pragma unroll
      for (int i = 0; i < 2; ++i)
        acc[i][j] = __builtin_amdgcn_mfma_f32_16x16x32_bf16(
            ah[i], blv[j], acc[i][j], 0, 0, 0);
  }
  __syncthreads();                      // scL writes visible (also from loop)

  const float rs = 0.04419417382415922f;  // 512^-0.5
  // scale + diag; value at (ai,bj,r): i = i0+ai*16+q*4+r, j = w*64+bj*16+c
#pragma unroll
  for (int ai = 0; ai < 2; ++ai)
#pragma unroll
    for (int bj = 0; bj < 4; ++bj)
#pragma unroll
      for (int r = 0; r < 4; ++r) {
        int i = i0 + ai * 16 + q * 4 + r;
        int j = w * 64 + bj * 16 + c;
        float sv = acc[ai][bj][r] * scL[j] * rs;
        if (j == i) sv = -0.0005f;
        acc[ai][bj][r] = sv;
      }
  // wave-local row max (over this wave's 64 j), then cross-wave via red
  float mx[2][4];
#pragma unroll
  for (int ai = 0; ai < 2; ++ai)
#pragma unroll
    for (int r = 0; r < 4; ++r) {
      float m = fmaxf(fmaxf(acc[ai][0][r], acc[ai][1][r]),
                      fmaxf(acc[ai][2][r], acc[ai][3][r]));
      m = fmaxf(m, __shfl_xor(m, 1));
      m = fmaxf(m, __shfl_xor(m, 2));
      m = fmaxf(m, __shfl_xor(m, 4));
      m = fmaxf(m, __shfl_xor(m, 8));
      mx[ai][r] = m;
    }
  if (c == 0) {
#pragma unroll
    for (int ai = 0; ai < 2; ++ai)
#pragma unroll
      for (int r = 0; r < 4; ++r) red[ai * 16 + q * 4 + r][w] = mx[ai][r];
  }
  __syncthreads();
#pragma unroll
  for (int ai = 0; ai < 2; ++ai)
#pragma unroll
    for (int r = 0; r < 4; ++r) {
      int row = ai * 16 + q * 4 + r;
      mx[ai][r] = fmaxf(fmaxf(red[row][0], red[row][1]),
                        fmaxf(red[row][2], red[row][3]));
    }
  __syncthreads();                      // before red reuse for sums
  float sm[2][4];
#pragma unroll
  for (int ai = 0; ai < 2; ++ai)
#pragma unroll
    for (int r = 0; r < 4; ++r) {
      float t = 0.f;
#pragma unroll
      for (int bj = 0; bj < 4; ++bj) {
        float e = expf(acc[ai][bj][r] - mx[ai][r]);
        acc[ai][bj][r] = e;
        t += e;
      }
      t += __shfl_xor(t, 1);
      t += __shfl_xor(t, 2);
      t += __shfl_xor(t, 4);
      t += __shfl_xor(t, 8);
      sm[ai][r] = t;
    }
  if (c == 0) {
#pragma unroll
    for (int ai = 0; ai < 2; ++ai)
#pragma unroll
      for (int r = 0; r < 4; ++r) red[ai * 16 + q * 4 + r][w] = sm[ai][r];
  }
  __syncthreads();
  float* ob = attnb + (size_t)bl * 65536;
#pragma unroll
  for (int ai = 0; ai < 2; ++ai)
#pragma unroll
    for (int r = 0; r < 4; ++r) {
      int row = ai * 16 + q * 4 + r;
      float S = red[row][0] + red[row][1] + red[row][2] + red[row][3];
      float inv = 1.0f / S;
      int i = i0 + row;
#pragma unroll
      for (int bj = 0; bj < 4; ++bj) {
        int j = w * 64 + bj * 16 + c;
        ob[(size_t)i * 256 + j] = acc[ai][bj][r] * inv;
      }
    }
}

// ---------------------------------------------------------------------------
// Consensus: accum += attnb @ lv (pure RMW). Grid 768, XCD-grouped by bl.
// ---------------------------------------------------------------------------
__global__ __launch_bounds__(256) void cons_k(
    const float* __restrict__ attnb, const float* __restrict__ lv,
    float* __restrict__ accum)
{
  __shared__ __align__(16) char smemraw[25088];
  const int a = blockIdx.x;
  const int s = a >> 3;
  const int bl = (a & 7) * 6 + (s >> 4);
  const int tile = s & 15;
  int it0 = (tile >> 2) * 64;
  int dt0 = (tile & 3) * 128;
  const float* A = attnb + (size_t)bl * 65536;
  const float* Bm = lv + (size_t)bl * 131072;
  float (*Ast)[68] = (float(*)[68])smemraw;
  float (*Bs)[128] = (float(*)[128])(smemraw + 8704);
  const int tid = threadIdx.x;
  const int ty = tid >> 4, tx = tid & 15;
  float acc[4][8];
#pragma unroll
  for (int i = 0; i < 4; ++i)
#pragma unroll
    for (int j = 0; j < 8; ++j) acc[i][j] = 0.f;

  for (int k0 = 0; k0 < 256; k0 += 32) {
#pragma unroll
    for (int it = 0; it < 2; ++it) {
      int f = it * 256 + tid;
      int r = f >> 3, c4 = f & 7;
      float4 v = *(const float4*)(A + (size_t)(it0 + r) * 256 + k0 + c4 * 4);
      Ast[c4 * 4 + 0][r] = v.x;
      Ast[c4 * 4 + 1][r] = v.y;
      Ast[c4 * 4 + 2][r] = v.z;
      Ast[c4 * 4 + 3][r] = v.w;
    }
#pragma unroll
    for (int it = 0; it < 4; ++it) {
      int kr = (tid >> 5) + it * 8;
      int c4 = tid & 31;
      *(float4*)&Bs[kr][c4 * 4] =
          *(const float4*)(Bm + (size_t)(k0 + kr) * 512 + dt0 + c4 * 4);
    }
    __syncthreads();
#pragma unroll 8
    for (int k = 0; k < 32; ++k) {
      float4 av = *(const float4*)&Ast[k][ty * 4];
      float4 b0 = *(const float4*)&Bs[k][tx * 4];
      float4 b1 = *(const float4*)&Bs[k][64 + tx * 4];
      float avv[4] = {av.x, av.y, av.z, av.w};
      float bv[8] = {b0.x, b0.y, b0.z, b0.w, b1.x, b1.y, b1.z, b1.w};
#pragma unroll
      for (int i = 0; i < 4; ++i)
#pragma unroll
        for (int j = 0; j < 8; ++j)
          acc[i][j] = fmaf(avv[i], bv[j], acc[i][j]);
    }
    __syncthreads();
  }
#pragma unroll
  for (int ii = 0; ii < 4; ++ii) {
    int i = it0 + ty * 4 + ii;
    float* arow = accum + (size_t)bl * 131072 + (size_t)i * 512 + dt0;
#pragma unroll
    for (int j = 0; j < 4; ++j) arow[tx * 4 + j] += acc[ii][j];
#pragma unroll
    for (int j = 0; j < 4; ++j) arow[64 + tx * 4 + j] += acc[ii][4 + j];
  }
}

// ---------------------------------------------------------------------------
// FF2 r12: 64(token) x 128(outd) block, 640 blocks, LDS-staged (r8 proved
// flat thrashes L2 here). h now SINGLE bf16: SA 2048 shorts (4KB), one
// A-gload per step, two MFMA passes (h*W2hi + h*W2lo) = 16 MFMA/step.
//  emode 0 (bu):      accum = lv + v            (store, levels 1..5)
//  emode 1 (td):      l==0: accum=lv+tokens+v;  else accum += v
// ---------------------------------------------------------------------------
__global__ __launch_bounds__(256, 4) void mfma_ff2(
    const short* __restrict__ hpk, const short* __restrict__ Wb,
    const float* __restrict__ b2, const float* __restrict__ lv,
    const float* __restrict__ tokens, float* __restrict__ accum,
    int olvbase, int emode)
{
  const int per_x = gridDim.x >> 3;
  const int gid = (blockIdx.x & 7) * per_x + (blockIdx.x >> 3);
  const int nt2 = gid & 3;
  const int tile = gid >> 2;
  const int mt2 = tile & 31;          // 64-token tiles
  const int z = tile >> 5;

  __shared__ __align__(16) short SA[2048];   // h single bf16, 4 frags
  __shared__ __align__(16) short SB[8192];   // W2 hi 4096 | lo 4096
  const int tid = threadIdx.x, lane = tid & 63, w = tid >> 6;
  const int wm = (w >> 1) * 32, wn = (w & 1) * 64;
  const short* gaBase = hpk + (size_t)(z * 16 + (mt2 >> 1)) * 64 * 4096
                        + (size_t)(mt2 & 1) * 2048;
  const short* gb = Wb + (size_t)(z * 4 + nt2) * 64 * 8192;

  f32x4 acc[2][4];
#pragma unroll
  for (int i = 0; i < 2; ++i)
#pragma unroll
    for (int j = 0; j < 4; ++j) acc[i][j] = (f32x4)(0.0f);

  for (int kt = 0; kt < 64; ++kt) {
    __syncthreads();
    const char* pa = (const char*)(gaBase + (size_t)kt * 4096);
    const char* pb = (const char*)(gb + (size_t)kt * 8192);
    gload16(pa + w * 1024 + lane * 16, (char*)SA + w * 1024);
#pragma unroll
    for (int c = 0; c < 4; ++c)
      gload16(pb + w * 4096 + c * 1024 + lane * 16,
              (char*)SB + w * 4096 + c * 1024);
    __syncthreads();
    bf16x8 ah[2];
#pragma unroll
    for (int i = 0; i < 2; ++i) {
      int f = (wm >> 4) + i;
      ah[i] = *(const bf16x8*)&SA[f * 512 + lane * 8];
    }
#pragma unroll
    for (int jp = 0; jp < 2; ++jp) {
      bf16x8 bh[2], bl[2];
#pragma unroll
      for (int j2 = 0; j2 < 2; ++j2) {
        int f = (wn >> 4) + jp * 2 + j2;
        bh[j2] = *(const bf16x8*)&SB[f * 512 + lane * 8];
        bl[j2] = *(const bf16x8*)&SB[4096 + f * 512 + lane * 8];
      }
      // pass 1: h * W2_hi
#pragma unroll
      for (int j2 = 0; j2 < 2; ++j2)
#pragma unroll
        for (int i = 0; i < 2; ++i)
          acc[i][jp * 2 + j2] = __builtin_amdgcn_mfma_f32_16x16x32_bf16(
              ah[i], bh[j2], acc[i][jp * 2 + j2], 0, 0, 0);
      // pass 2: h * W2_lo
#pragma unroll
      for (int j2 = 0; j2 < 2; ++j2)
#pragma unroll
        for (int i = 0; i < 2; ++i)
          acc[i][jp * 2 + j2] = __builtin_amdgcn_mfma_f32_16x16x32_bf16(
              ah[i], bl[j2], acc[i][jp * 2 + j2], 0, 0, 0);
    }
  }

  const int q = lane >> 4, t = lane & 15;
  const float* b2g = b2 + (size_t)z * 512;
  const int level = olvbase + z;
#pragma unroll
  for (int i = 0; i < 2; ++i) {
#pragma unroll
    for (int r = 0; r < 4; ++r) {
      int m = mt2 * 64 + wm + i * 16 + q * 4 + r;
      int b = m >> 8, n = m & 255;
      size_t rowoff = ((size_t)(b * L6 + level) * 256 + n) * 512;
      float* arow = accum + rowoff;
      const float* lrow = lv + rowoff;
      const float* trow = tokens + (size_t)m * 512;
#pragma unroll
      for (int j = 0; j < 4; ++j) {
        int col = nt2 * 128 + wn + j * 16 + t;
        float v = acc[i][j][r] + b2g[col];
        if (emode == 0)                       arow[col] = lrow[col] + v;
        else if (level == 0)                  arow[col] = lrow[col] + trow[col] + v;
        else                                  arow[col] += v;
      }
    }
  }
}

// ---------------------------------------------------------------------------
// combine3: lv = accum/contrib, write dout on last iter, fused next-iter
// A-packing, and fused exact-fp32 row-norm via 64-lane butterfly.
// ---------------------------------------------------------------------------
__global__ __launch_bounds__(256) void combine3(
    const float* __restrict__ accum, const float* __restrict__ pos,
    float* __restrict__ lv_out, short* __restrict__ Abu,
    short* __restrict__ Atd, float* __restrict__ invn,
    float* __restrict__ dout, int last)
{
  int t = blockIdx.x * 256 + threadIdx.x;   // 786,432 total
  int d8 = t & 63;
  int n = (t >> 6) & 255;
  int v = t >> 14;                          // b*6 + l, 0..47
  int l = v % 6, b = v / 6;
  int bn = (b << 8) | n;
  size_t idx = ((size_t)v * 256 + n) * 512 + d8 * 8;
  float4 a0 = *(const float4*)(accum + idx);
  float4 a1 = *(const float4*)(accum + idx + 4);
  float sc = (l == 5) ? (1.0f / 3.0f) : 0.25f;
  float r[8];
  r[0] = a0.x * sc; r[1] = a0.y * sc; r[2] = a0.z * sc; r[3] = a0.w * sc;
  r[4] = a1.x * sc; r[5] = a1.y * sc; r[6] = a1.z * sc; r[7] = a1.w * sc;
  *(float4*)(lv_out + idx) = make_float4(r[0], r[1], r[2], r[3]);
  *(float4*)(lv_out + idx + 4) = make_float4(r[4], r[5], r[6], r[7]);
  if (last) {
    float* dp = dout + ((size_t)bn * 6 + l) * 512 + d8 * 8;
    *(float4*)dp = make_float4(r[0], r[1], r[2], r[3]);
    *(float4*)(dp + 4) = make_float4(r[4], r[5], r[6], r[7]);
  }
  // fused row norm: wave == one (v,n) row (d8 = lane)
  {
    float s8 = 0.f;
#pragma unroll
    for (int j = 0; j < 8; ++j) s8 = fmaf(r[j], r[j], s8);
#pragma unroll
    for (int o = 1; o < 64; o <<= 1) s8 += __shfl_xor(s8, o);
    if (d8 == 0) invn[(size_t)v * 256 + n] = 1.0f / fmaxf(sqrtf(s8), 1e-12f);
  }
  int m = bn;
  int mt = m >> 7;
  int kt = d8 >> 2;
  int s = (((m & 127) >> 4) << 6) | (((d8 & 3) << 4) | (m & 15));
  unsigned short hi[8], lo[8];
  if (l < 5) {
    size_t blk = ((size_t)(l * 16 + mt) * 16 + kt) * 8192;
#pragma unroll
    for (int j = 0; j < 8; ++j) split2(r[j], &hi[j], &lo[j]);
    *(int4*)(Abu + blk + s * 8) = pack8(hi);
    *(int4*)(Abu + blk + 4096 + s * 8) = pack8(lo);
  }
  if (l >= 1) {
    const float* pp = pos + (size_t)n * 512 + d8 * 8;
    float4 p0 = *(const float4*)pp;
    float4 p1 = *(const float4*)(pp + 4);
    float y[8] = {r[0] + p0.x, r[1] + p0.y, r[2] + p0.z, r[3] + p0.w,
                  r[4] + p1.x, r[5] + p1.y, r[6] + p1.z, r[7] + p1.w};
    size_t blk = ((size_t)((l - 1) * 16 + mt) * 16 + kt) * 8192;
#pragma unroll
    for (int j = 0; j < 8; ++j) split2(y[j], &hi[j], &lo[j]);
    *(int4*)(Atd + blk + s * 8) = pack8(hi);
    *(int4*)(Atd + blk + 4096 + s * 8) = pack8(lo);
  }
}

// ---------------------------------------------------------------------------
extern "C" void kernel_launch(void* const* d_in, const int* in_sizes, int n_in,
                              void* d_out, int out_size, void* d_ws, size_t ws_size,
                              hipStream_t stream)
{
  const float* img   = (const float*)d_in[0];
  const float* Wp    = (const float*)d_in[1];
  const float* bp    = (const float*)d_in[2];
  const float* pos   = (const float*)d_in[3];
  const float* initl = (const float*)d_in[4];
  const float* buW1  = (const float*)d_in[5];
  const float* bub1  = (const float*)d_in[6];
  const float* buW2  = (const float*)d_in[7];
  const float* bub2  = (const float*)d_in[8];
  const float* tdW1  = (const float*)d_in[9];
  const float* tdb1  = (const float*)d_in[10];
  const float* tdW2  = (const float*)d_in[11];
  const float* tdb2  = (const float*)d_in[12];

  float* ws = (float*)d_ws;
  const size_t LV = (size_t)8 * 6 * 256 * 512;   // 6,291,456 floats
  float* lv     = ws;
  float* tokens = lv + LV;                        // 1,048,576
  float* accum  = tokens + 1048576ull;            // 6,291,456
  short* W1all  = (short*)(accum + LV);           // 20,971,520 shorts
  short* W2all  = W1all + 20971520ull;            // 20,971,520 shorts
  short* Apk    = W2all + 20971520ull;            // 20,971,520 shorts
  short* hall   = Apk + 20971520ull;              // r12: 20,971,520 shorts (hi only)
  float* invn   = (float*)(hall + 41943040ull);   // 48*256 f32 = 49,152 B
  // total unchanged = 264,290,304 B == proven capacity

  // attnb sits at hall+20,971,520 shorts — beyond hall's (now halved) extent.
  float* attnb = (float*)(hall + 20971520ull);
  float* dout  = (float*)d_out;

  pack_w<<<2560, 256, 0, stream>>>(buW1, W1all, 16, 16);
  pack_w<<<2560, 256, 0, stream>>>(tdW1, W1all + 5 * SH_W_GRP, 16, 16);
  pack_w<<<2560, 256, 0, stream>>>(buW2, W2all, 64, 4);
  pack_w<<<2560, 256, 0, stream>>>(tdW2, W2all + 5 * SH_W_GRP, 64, 4);

  patch_embed<<<2048, 256, 0, stream>>>(img, Wp, bp, tokens);
  init_lv_kernel<<<6144, 256, 0, stream>>>(initl, lv);
  norm0_k<<<48, 256, 0, stream>>>(lv, invn);
  pack_A<<<1280, 256, 0, stream>>>(lv, pos, Apk, Apk + SH_A_TDOFF);

  for (int it = 0; it < 12; ++it) {
    // K1: ff1-bu (fills hall, single-bf16 h)
    ff1_k<<<1280, 256, 0, stream>>>(W1all, Apk, bub1, hall);
    // K2: ff2-bu emode0 (store accum = lv + v, levels 1..5)
    mfma_ff2<<<640, 256, 0, stream>>>(hall, W2all, bub2, lv, tokens, accum, 1, 0);
    // K3: ff1-td (refills hall)
    ff1_k<<<1280, 256, 0, stream>>>(W1all + 5 * SH_W_GRP, Apk + SH_A_TDOFF,
                                    tdb1, hall);
    // K4: ff2-td emode1 (level0 store lv+tokens+v; levels 1..4 RMW)
    mfma_ff2<<<640, 256, 0, stream>>>(hall, W2all + 5 * SH_W_GRP, tdb2, lv,
                                      tokens, accum, 0, 1);
    // K5: MFMA attention (reads Apk bu-image + invn; lv only for level 5)
    attn_k<<<384, 256, 0, stream>>>(lv, Apk, invn, attnb);
    // K6: consensus RMW into accum
    cons_k<<<768, 256, 0, stream>>>(attnb, lv, accum);
    // K7: combine + dout + next-iter A-pack + fused norms
    combine3<<<3072, 256, 0, stream>>>(accum, pos, lv, Apk, Apk + SH_A_TDOFF,
                                       invn, dout, it == 11 ? 1 : 0);
  }
}

// Round 13
// 3915.268 us; speedup vs baseline: 1.3643x; 1.0633x over previous
//
#include <hip/hip_runtime.h>
#include <math.h>

// Problem constants: B=8, S=224, P=14, D=512, L=6, NPS=16, N=256, G=5, H=2048, iters=12
#define L6 6

typedef __attribute__((ext_vector_type(8))) short bf16x8;   // 8 bf16 in 4 VGPRs
typedef __attribute__((ext_vector_type(4))) float f32x4;    // MFMA accum

#define SH_W_GRP   2097152ull   // 512*2048 hi/lo bf16 (both W1 and W2)
#define SH_A_TDOFF 10485760ull  // Atd offset inside Apk (5 groups)

// Exact gelu (erff): r10-proven epilogue.
__device__ __forceinline__ float gelu_exact(float x) {
  return 0.5f * x * (1.0f + erff(x * 0.70710678118654752f));
}

__device__ __forceinline__ unsigned short bf16_rn(float x) {
  unsigned u = __float_as_uint(x);
  unsigned r = u + 0x7FFFu + ((u >> 16) & 1u);
  return (unsigned short)(r >> 16);
}
__device__ __forceinline__ float bf16_f(unsigned short h) {
  return __uint_as_float(((unsigned)h) << 16);
}
__device__ __forceinline__ void split2(float x, unsigned short* h, unsigned short* l) {
  unsigned short hh = bf16_rn(x);
  *h = hh;
  *l = bf16_rn(x - bf16_f(hh));
}
__device__ __forceinline__ int4 pack8(const unsigned short* v) {
  return make_int4((int)((unsigned)v[0] | ((unsigned)v[1] << 16)),
                   (int)((unsigned)v[2] | ((unsigned)v[3] << 16)),
                   (int)((unsigned)v[4] | ((unsigned)v[5] << 16)),
                   (int)((unsigned)v[6] | ((unsigned)v[7] << 16)));
}

__device__ __forceinline__ void gload16(const void* g, void* l) {
  __builtin_amdgcn_global_load_lds(
      (const __attribute__((address_space(1))) void*)g,
      (__attribute__((address_space(3))) void*)l, 16, 0, 0);
}

// ---------------------------------------------------------------------------
// Patch embedding r13: k-split x2 + float4 Wp loads (was 1176 scalar loads/
// thread -> 294 float4; 4 indep accum chains). fp32 association change only.
// ---------------------------------------------------------------------------
__global__ __launch_bounds__(256) void patch_embed(
    const float* __restrict__ img, const float* __restrict__ Wp,
    const float* __restrict__ bp, float* __restrict__ tokens)
{
  __shared__ float xs[588];
  __shared__ float part[128][4];
  const int bn = blockIdx.x;
  const int b = bn >> 8, n = bn & 255;
  const int i = n >> 4, j = n & 15;
  for (int k = threadIdx.x; k < 588; k += 256) {
    int c = k % 3;
    int t = k / 3;
    int pc = t % 14;
    int pr = t / 14;
    xs[k] = img[(((size_t)(b * 3 + c) * 224) + (i * 14 + pr)) * 224 + (j * 14 + pc)];
  }
  __syncthreads();
  const int kh = threadIdx.x >> 7;       // 0/1 k-half
  const int dq = threadIdx.x & 127;
  const int d0 = dq * 4;
  float a0 = 0.f, a1 = 0.f, a2 = 0.f, a3 = 0.f;
  const int kbeg = kh * 294, kend = kbeg + 294;
  for (int k = kbeg; k < kend; ++k) {
    float x = xs[k];
    float4 wv = *(const float4*)(Wp + (size_t)k * 512 + d0);
    a0 = fmaf(x, wv.x, a0);
    a1 = fmaf(x, wv.y, a1);
    a2 = fmaf(x, wv.z, a2);
    a3 = fmaf(x, wv.w, a3);
  }
  if (kh == 0) {
    part[dq][0] = a0; part[dq][1] = a1; part[dq][2] = a2; part[dq][3] = a3;
  }
  __syncthreads();
  if (kh == 1) {
    float4 bv = *(const float4*)(bp + d0);
    float4 o = make_float4(part[dq][0] + a0 + bv.x, part[dq][1] + a1 + bv.y,
                           part[dq][2] + a2 + bv.z, part[dq][3] + a3 + bv.w);
    *(float4*)(tokens + (size_t)bn * 512 + d0) = o;
  }
}

// ---------------------------------------------------------------------------
__global__ __launch_bounds__(256) void init_lv_kernel(
    const float* __restrict__ initl, float* __restrict__ lv)
{
  int f = blockIdx.x * 256 + threadIdx.x;
  int d4 = f & 127;
  int l = (f >> 15) % 6;
  float4 v = *(const float4*)(initl + (size_t)l * 512 + d4 * 4);
  *(float4*)(lv + (size_t)f * 4) = v;
}

// ---------------------------------------------------------------------------
// Startup norms (steady-state fused into combine3).
// ---------------------------------------------------------------------------
__global__ __launch_bounds__(256) void norm0_k(
    const float* __restrict__ lv, float* __restrict__ invn)
{
  int bl = blockIdx.x;
  int n = threadIdx.x;
  const float* row = lv + ((size_t)bl * 256 + n) * 512;
  float ss = 0.f;
  for (int k = 0; k < 512; k += 4) {
    float4 v = *(const float4*)(row + k);
    ss = fmaf(v.x, v.x, ss);
    ss = fmaf(v.y, v.y, ss);
    ss = fmaf(v.z, v.z, ss);
    ss = fmaf(v.w, v.w, ss);
  }
  invn[(size_t)bl * 256 + n] = 1.0f / fmaxf(sqrtf(ss), 1e-12f);
}

// ---------------------------------------------------------------------------
// Pack weights fp32 [G][K][N] -> hi/lo bf16 fragment-image.
// ---------------------------------------------------------------------------
__global__ __launch_bounds__(256) void pack_w(
    const float* __restrict__ src, short* __restrict__ dst, int KT, int NT)
{
  int sidx = blockIdx.x * 256 + threadIdx.x;
  int slot = sidx & 511;
  int blk = sidx >> 9;
  int kt = blk % KT;
  int rest = blk / KT;
  int nt = rest % NT;
  int g = rest / NT;
  int f = slot >> 6, lane = slot & 63;
  int N = NT * 128, K = KT * 32;
  int n = nt * 128 + f * 16 + (lane & 15);
  int k0 = kt * 32 + (lane >> 4) * 8;
  const float* s = src + ((size_t)g * K + k0) * N + n;
  unsigned short hi[8], lo[8];
#pragma unroll
  for (int j = 0; j < 8; ++j) split2(s[(size_t)j * N], &hi[j], &lo[j]);
  short* d = dst + (size_t)blk * 8192 + slot * 8;
  *(int4*)d = pack8(hi);
  *(int4*)(d + 4096) = pack8(lo);
}

// ---------------------------------------------------------------------------
// Startup A-pack (steady-state fused into combine3).
// ---------------------------------------------------------------------------
__global__ __launch_bounds__(256) void pack_A(
    const float* __restrict__ lv, const float* __restrict__ pos,
    short* __restrict__ Abu, short* __restrict__ Atd)
{
  const int bx = blockIdx.x;              // 0..1279
  const int lg = bx >> 8, mt = (bx >> 4) & 15, kt = bx & 15;
  const size_t blk = (size_t)bx * 8192;
#pragma unroll
  for (int ss = 0; ss < 2; ++ss) {
    int s = threadIdx.x + ss * 256;
    int f = s >> 6, l = s & 63;
    int m = mt * 128 + (f << 4) + (l & 15);
    int b = m >> 8, n = m & 255;
    int d = kt * 32 + ((l >> 4) << 3);
    const float* pbu = lv + ((size_t)(b * L6 + lg) * 256 + n) * 512 + d;
    const float* ptd = lv + ((size_t)(b * L6 + lg + 1) * 256 + n) * 512 + d;
    const float* pp = pos + (size_t)n * 512 + d;
    float4 u0 = *(const float4*)pbu;
    float4 u1 = *(const float4*)(pbu + 4);
    float xv[8] = {u0.x, u0.y, u0.z, u0.w, u1.x, u1.y, u1.z, u1.w};
    unsigned short hi[8], lo[8];
#pragma unroll
    for (int j = 0; j < 8; ++j) split2(xv[j], &hi[j], &lo[j]);
    *(int4*)(Abu + blk + s * 8) = pack8(hi);
    *(int4*)(Abu + blk + 4096 + s * 8) = pack8(lo);
    float4 v0 = *(const float4*)ptd;
    float4 v1 = *(const float4*)(ptd + 4);
    float4 p0 = *(const float4*)pp;
    float4 p1 = *(const float4*)(pp + 4);
    float yv[8] = {v0.x + p0.x, v0.y + p0.y, v0.z + p0.z, v0.w + p0.w,
                   v1.x + p1.x, v1.y + p1.y, v1.z + p1.z, v1.w + p1.w};
#pragma unroll
    for (int j = 0; j < 8; ++j) split2(yv[j], &hi[j], &lo[j]);
    *(int4*)(Atd + blk + s * 8) = pack8(hi);
    *(int4*)(Atd + blk + 4096 + s * 8) = pack8(lo);
  }
}

// ---------------------------------------------------------------------------
// FF1 body: flat GEMM 64x64 wave tiles, single-bf16 h out (r12-proven).
// ---------------------------------------------------------------------------
__device__ __forceinline__ void ff1_body(
    const short* __restrict__ Wa, const short* __restrict__ Ap,
    const float* __restrict__ b1, short* __restrict__ hpk, int gid)
{
  const int tt = gid & 15;
  const int tile = gid >> 4;
  const int ht = tile & 15;
  const int z = tile >> 4;
  const int tid = threadIdx.x, lane = tid & 63, w = tid >> 6;
  const int wm = (w >> 1) * 64, wn = (w & 1) * 64;
  const short* ga = Wa + (size_t)(z * 16 + ht) * 16 * 8192 + (wm << 5) + lane * 8;
  const short* gb = Ap + (size_t)(z * 16 + tt) * 16 * 8192 + (wn << 5) + lane * 8;

  f32x4 acc[4][4];
#pragma unroll
  for (int i = 0; i < 4; ++i)
#pragma unroll
    for (int j = 0; j < 4; ++j) acc[i][j] = (f32x4)(0.0f);

  for (int kt = 0; kt < 16; ++kt) {
    const short* pa = ga + (size_t)kt * 8192;
    const short* pb = gb + (size_t)kt * 8192;
    bf16x8 ah[4], al[4], bh[4], bl[4];
#pragma unroll
    for (int i = 0; i < 4; ++i) {
      ah[i] = *(const bf16x8*)(pa + i * 512);
      al[i] = *(const bf16x8*)(pa + 4096 + i * 512);
    }
#pragma unroll
    for (int j = 0; j < 4; ++j) {
      bh[j] = *(const bf16x8*)(pb + j * 512);
      bl[j] = *(const bf16x8*)(pb + 4096 + j * 512);
    }
#pragma unroll
    for (int j = 0; j < 4; ++j)
#pragma unroll
      for (int i = 0; i < 4; ++i)
        acc[i][j] = __builtin_amdgcn_mfma_f32_16x16x32_bf16(
            ah[i], bh[j], acc[i][j], 0, 0, 0);
#pragma unroll
    for (int j = 0; j < 4; ++j)
#pragma unroll
      for (int i = 0; i < 4; ++i)
        acc[i][j] = __builtin_amdgcn_mfma_f32_16x16x32_bf16(
            al[i], bh[j], acc[i][j], 0, 0, 0);
#pragma unroll
    for (int j = 0; j < 4; ++j)
#pragma unroll
      for (int i = 0; i < 4; ++i)
        acc[i][j] = __builtin_amdgcn_mfma_f32_16x16x32_bf16(
            ah[i], bl[j], acc[i][j], 0, 0, 0);
  }

  const int q = lane >> 4, t = lane & 15;
  const float* b1g = b1 + (size_t)z * 2048;
#pragma unroll
  for (int i = 0; i < 4; ++i) {
    int Hb = ht * 128 + wm + i * 16 + q * 4;
    float4 bv = *(const float4*)(b1g + Hb);
    float bb[4] = {bv.x, bv.y, bv.z, bv.w};
    int kt2 = Hb >> 5;
    int g2 = (Hb >> 3) & 3;
    int jb = Hb & 7;                       // 0 or 4
    size_t blkbase = ((size_t)(z * 16 + tt) * 64 + kt2) * 4096;
#pragma unroll
    for (int j = 0; j < 4; ++j) {
      int f2 = (wn >> 4) + j;
      size_t off = blkbase + (size_t)(f2 * 64 + g2 * 16 + t) * 8 + jb;
      unsigned short hi[4];
#pragma unroll
      for (int r = 0; r < 4; ++r)
        hi[r] = bf16_rn(gelu_exact(acc[i][j][r] + bb[r]));
      *(uint2*)(hpk + off) =
          make_uint2((unsigned)hi[0] | ((unsigned)hi[1] << 16),
                     (unsigned)hi[2] | ((unsigned)hi[3] << 16));
    }
  }
}

// ---------------------------------------------------------------------------
// FF2 body: LDS-staged, single-bf16 h in, hi/lo W2 (r12-proven).
// smem layout: SA short[2048] @0, SB short[8192] @4096B (20480 B total).
// ---------------------------------------------------------------------------
__device__ __forceinline__ void ff2_body(
    char* smem, const short* __restrict__ hpk, const short* __restrict__ Wb,
    const float* __restrict__ b2, const float* __restrict__ lv,
    const float* __restrict__ tokens, float* __restrict__ accum,
    int olvbase, int emode, int gid)
{
  short* SA = (short*)smem;
  short* SB = (short*)(smem + 4096);
  const int nt2 = gid & 3;
  const int tile = gid >> 2;
  const int mt2 = tile & 31;          // 64-token tiles
  const int z = tile >> 5;

  const int tid = threadIdx.x, lane = tid & 63, w = tid >> 6;
  const int wm = (w >> 1) * 32, wn = (w & 1) * 64;
  const short* gaBase = hpk + (size_t)(z * 16 + (mt2 >> 1)) * 64 * 4096
                        + (size_t)(mt2 & 1) * 2048;
  const short* gb = Wb + (size_t)(z * 4 + nt2) * 64 * 8192;

  f32x4 acc[2][4];
#pragma unroll
  for (int i = 0; i < 2; ++i)
#pragma unroll
    for (int j = 0; j < 4; ++j) acc[i][j] = (f32x4)(0.0f);

  for (int kt = 0; kt < 64; ++kt) {
    __syncthreads();
    const char* pa = (const char*)(gaBase + (size_t)kt * 4096);
    const char* pb = (const char*)(gb + (size_t)kt * 8192);
    gload16(pa + w * 1024 + lane * 16, (char*)SA + w * 1024);
#pragma unroll
    for (int c = 0; c < 4; ++c)
      gload16(pb + w * 4096 + c * 1024 + lane * 16,
              (char*)SB + w * 4096 + c * 1024);
    __syncthreads();
    bf16x8 ah[2];
#pragma unroll
    for (int i = 0; i < 2; ++i) {
      int f = (wm >> 4) + i;
      ah[i] = *(const bf16x8*)&SA[f * 512 + lane * 8];
    }
#pragma unroll
    for (int jp = 0; jp < 2; ++jp) {
      bf16x8 bh[2], bl[2];
#pragma unroll
      for (int j2 = 0; j2 < 2; ++j2) {
        int f = (wn >> 4) + jp * 2 + j2;
        bh[j2] = *(const bf16x8*)&SB[f * 512 + lane * 8];
        bl[j2] = *(const bf16x8*)&SB[4096 + f * 512 + lane * 8];
      }
#pragma unroll
      for (int j2 = 0; j2 < 2; ++j2)
#pragma unroll
        for (int i = 0; i < 2; ++i)
          acc[i][jp * 2 + j2] = __builtin_amdgcn_mfma_f32_16x16x32_bf16(
              ah[i], bh[j2], acc[i][jp * 2 + j2], 0, 0, 0);
#pragma unroll
      for (int j2 = 0; j2 < 2; ++j2)
#pragma unroll
        for (int i = 0; i < 2; ++i)
          acc[i][jp * 2 + j2] = __builtin_amdgcn_mfma_f32_16x16x32_bf16(
              ah[i], bl[j2], acc[i][jp * 2 + j2], 0, 0, 0);
    }
  }

  const int q = lane >> 4, t = lane & 15;
  const float* b2g = b2 + (size_t)z * 512;
  const int level = olvbase + z;
#pragma unroll
  for (int i = 0; i < 2; ++i) {
#pragma unroll
    for (int r = 0; r < 4; ++r) {
      int m = mt2 * 64 + wm + i * 16 + q * 4 + r;
      int b = m >> 8, n = m & 255;
      size_t rowoff = ((size_t)(b * L6 + level) * 256 + n) * 512;
      float* arow = accum + rowoff;
      const float* lrow = lv + rowoff;
      const float* trow = tokens + (size_t)m * 512;
#pragma unroll
      for (int j = 0; j < 4; ++j) {
        int col = nt2 * 128 + wn + j * 16 + t;
        float v = acc[i][j][r] + b2g[col];
        if (emode == 0)                       arow[col] = lrow[col] + v;
        else if (level == 0)                  arow[col] = lrow[col] + trow[col] + v;
        else                                  arow[col] += v;
      }
    }
  }
}

// ---------------------------------------------------------------------------
// Attention body (r7-proven): MFMA Gram + norm table.
// smem: Bhi short[8192] @0, Blo short[8192] @16384, scL float[256] @32768,
// red float[32][4] @33792 (34304 B total).
// ---------------------------------------------------------------------------
__device__ __forceinline__ void attn_body(
    char* smem, const float* __restrict__ lv, const short* __restrict__ Apk,
    const float* __restrict__ invn, float* __restrict__ attnb, int a)
{
  short* Bhi = (short*)smem;
  short* Blo = (short*)(smem + 16384);
  float* scL = (float*)(smem + 32768);
  float (*red)[4] = (float(*)[4])(smem + 33792);
  const int s = a >> 3;
  const int b = a & 7;                 // batch == XCD group
  const int l = s >> 3;                // level 0..5
  const int bl = b * 6 + l;
  const int i0 = (s & 7) * 32;
  const float* base = lv + (size_t)bl * 131072;
  const int tid = threadIdx.x, lane = tid & 63, w = tid >> 6;
  const int q = lane >> 4, c = lane & 15;

  scL[tid] = invn[(size_t)bl * 256 + tid];

  f32x4 acc[2][4];
#pragma unroll
  for (int i = 0; i < 2; ++i)
#pragma unroll
    for (int j = 0; j < 4; ++j) acc[i][j] = (f32x4)(0.0f);

  const short* src0 = Apk + ((size_t)(l * 16 + 2 * b) * 16) * 8192;
  const short* src1 = Apk + ((size_t)(l * 16 + 2 * b + 1) * 16) * 8192;

  for (int kt = 0; kt < 16; ++kt) {
    __syncthreads();
    if (l < 5) {
      const char* p0 = (const char*)(src0 + (size_t)kt * 8192);
      const char* p1 = (const char*)(src1 + (size_t)kt * 8192);
      gload16(p0 + tid * 16,         (char*)Bhi + tid * 16);
      gload16(p0 + 4096 + tid * 16,  (char*)Bhi + 4096 + tid * 16);
      gload16(p0 + 8192 + tid * 16,  (char*)Blo + tid * 16);
      gload16(p0 + 12288 + tid * 16, (char*)Blo + 4096 + tid * 16);
      gload16(p1 + tid * 16,         (char*)Bhi + 8192 + tid * 16);
      gload16(p1 + 4096 + tid * 16,  (char*)Bhi + 12288 + tid * 16);
      gload16(p1 + 8192 + tid * 16,  (char*)Blo + 8192 + tid * 16);
      gload16(p1 + 12288 + tid * 16, (char*)Blo + 12288 + tid * 16);
    } else {
      const int k0 = kt * 32;
#pragma unroll
      for (int it = 0; it < 8; ++it) {
        int f = it * 256 + tid;
        int j = f >> 3, c4 = f & 7;
        float4 v = *(const float4*)(base + (size_t)j * 512 + k0 + c4 * 4);
        unsigned short hi[4], lo[4];
        split2(v.x, &hi[0], &lo[0]);
        split2(v.y, &hi[1], &lo[1]);
        split2(v.z, &hi[2], &lo[2]);
        split2(v.w, &hi[3], &lo[3]);
        int fg = j >> 4;
        int la = (c4 >> 1) * 16 + (j & 15);
        int half = (c4 & 1) * 4;
        *(uint2*)&Bhi[fg * 512 + la * 8 + half] =
            make_uint2((unsigned)hi[0] | ((unsigned)hi[1] << 16),
                       (unsigned)hi[2] | ((unsigned)hi[3] << 16));
        *(uint2*)&Blo[fg * 512 + la * 8 + half] =
            make_uint2((unsigned)lo[0] | ((unsigned)lo[1] << 16),
                       (unsigned)lo[2] | ((unsigned)lo[3] << 16));
      }
    }
    __syncthreads();
    bf16x8 ah[2], al[2], bh[4], blv[4];
#pragma unroll
    for (int i = 0; i < 2; ++i) {
      int fg = (i0 >> 4) + i;
      ah[i] = *(const bf16x8*)&Bhi[fg * 512 + lane * 8];
      al[i] = *(const bf16x8*)&Blo[fg * 512 + lane * 8];
    }
#pragma unroll
    for (int j = 0; j < 4; ++j) {
      int fg = w * 4 + j;
      bh[j] = *(const bf16x8*)&Bhi[fg * 512 + lane * 8];
      blv[j] = *(const bf16x8*)&Blo[fg * 512 + lane * 8];
    }
#pragma unroll
    for (int j = 0; j < 4; ++j)
#pragma unroll
      for (int i = 0; i < 2; ++i)
        acc[i][j] = __builtin_amdgcn_mfma_f32_16x16x32_bf16(
            ah[i], bh[j], acc[i][j], 0, 0, 0);
#pragma unroll
    for (int j = 0; j < 4; ++j)
#pragma unroll
      for (int i = 0; i < 2; ++i)
        acc[i][j] = __builtin_amdgcn_mfma_f32_16x16x32_bf16(
            al[i], bh[j], acc[i][j], 0, 0, 0);
#pragma unroll
    for (int j = 0; j < 4; ++j)
#pragma unroll
      for (int i = 0; i < 2; ++i)
        acc[i][j] = __builtin_amdgcn_mfma_f32_16x16x32_bf16(
            ah[i], blv[j], acc[i][j], 0, 0, 0);
  }
  __syncthreads();

  const float rs = 0.04419417382415922f;  // 512^-0.5
#pragma unroll
  for (int ai = 0; ai < 2; ++ai)
#pragma unroll
    for (int bj = 0; bj < 4; ++bj)
#pragma unroll
      for (int r = 0; r < 4; ++r) {
        int i = i0 + ai * 16 + q * 4 + r;
        int j = w * 64 + bj * 16 + c;
        float sv = acc[ai][bj][r] * scL[j] * rs;
        if (j == i) sv = -0.0005f;
        acc[ai][bj][r] = sv;
      }
  float mx[2][4];
#pragma unroll
  for (int ai = 0; ai < 2; ++ai)
#pragma unroll
    for (int r = 0; r < 4; ++r) {
      float m = fmaxf(fmaxf(acc[ai][0][r], acc[ai][1][r]),
                      fmaxf(acc[ai][2][r], acc[ai][3][r]));
      m = fmaxf(m, __shfl_xor(m, 1));
      m = fmaxf(m, __shfl_xor(m, 2));
      m = fmaxf(m, __shfl_xor(m, 4));
      m = fmaxf(m, __shfl_xor(m, 8));
      mx[ai][r] = m;
    }
  if (c == 0) {
#pragma unroll
    for (int ai = 0; ai < 2; ++ai)
#pragma unroll
      for (int r = 0; r < 4; ++r) red[ai * 16 + q * 4 + r][w] = mx[ai][r];
  }
  __syncthreads();
#pragma unroll
  for (int ai = 0; ai < 2; ++ai)
#pragma unroll
    for (int r = 0; r < 4; ++r) {
      int row = ai * 16 + q * 4 + r;
      mx[ai][r] = fmaxf(fmaxf(red[row][0], red[row][1]),
                        fmaxf(red[row][2], red[row][3]));
    }
  __syncthreads();
  float sm[2][4];
#pragma unroll
  for (int ai = 0; ai < 2; ++ai)
#pragma unroll
    for (int r = 0; r < 4; ++r) {
      float t = 0.f;
#pragma unroll
      for (int bj = 0; bj < 4; ++bj) {
        float e = expf(acc[ai][bj][r] - mx[ai][r]);
        acc[ai][bj][r] = e;
        t += e;
      }
      t += __shfl_xor(t, 1);
      t += __shfl_xor(t, 2);
      t += __shfl_xor(t, 4);
      t += __shfl_xor(t, 8);
      sm[ai][r] = t;
    }
  if (c == 0) {
#pragma unroll
    for (int ai = 0; ai < 2; ++ai)
#pragma unroll
      for (int r = 0; r < 4; ++r) red[ai * 16 + q * 4 + r][w] = sm[ai][r];
  }
  __syncthreads();
  float* ob = attnb + (size_t)bl * 65536;
#pragma unroll
  for (int ai = 0; ai < 2; ++ai)
#pragma unroll
    for (int r = 0; r < 4; ++r) {
      int row = ai * 16 + q * 4 + r;
      float S = red[row][0] + red[row][1] + red[row][2] + red[row][3];
      float inv = 1.0f / S;
      int i = i0 + row;
#pragma unroll
      for (int bj = 0; bj < 4; ++bj) {
        int j = w * 64 + bj * 16 + c;
        ob[(size_t)i * 256 + j] = acc[ai][bj][r] * inv;
      }
    }
}

// ---------------------------------------------------------------------------
// Standalone ff1 (K1: bu). Grid 1280.
// ---------------------------------------------------------------------------
__global__ __launch_bounds__(256, 3) void ff1_k(
    const short* __restrict__ Wa, const short* __restrict__ Ap,
    const float* __restrict__ b1, short* __restrict__ hpk)
{
  const int per_x = gridDim.x >> 3;
  const int gid = (blockIdx.x & 7) * per_x + (blockIdx.x >> 3);
  ff1_body(Wa, Ap, b1, hpk, gid);
}

// ---------------------------------------------------------------------------
// D2 r13: ff2-bu (blocks 0..639) CO-DISPATCHED with ff1-td (640..1919).
// Independent: ff2-bu reads hall_bu (from D1), ff1-td writes hall_td.
// Fills the machine across the former K2|K3 serialization point.
// ---------------------------------------------------------------------------
__global__ __launch_bounds__(256, 3) void k_ff2bu_ff1td(
    const short* __restrict__ hallbu, const short* __restrict__ W2,
    const float* __restrict__ bub2, const float* __restrict__ lv,
    const float* __restrict__ tokens, float* __restrict__ accum,
    const short* __restrict__ W1td, const short* __restrict__ Atd,
    const float* __restrict__ tdb1, short* __restrict__ halltd)
{
  __shared__ __align__(16) char smem[20480];
  if (blockIdx.x < 640) {
    int bid = blockIdx.x;
    int gid = (bid & 7) * 80 + (bid >> 3);
    ff2_body(smem, hallbu, W2, bub2, lv, tokens, accum, 1, 0, gid);
  } else {
    int bid = blockIdx.x - 640;
    int gid = (bid & 7) * 160 + (bid >> 3);
    ff1_body(W1td, Atd, tdb1, halltd, gid);
  }
}

// ---------------------------------------------------------------------------
// D3 r13: ff2-td (blocks 0..639) CO-DISPATCHED with attn (640..1023).
// Independent: attn reads lv/Apk/invn (stable), ff2-td reads hall_td.
// attnb aliases hall_bu (dead after D2's ff2-bu).
// ---------------------------------------------------------------------------
__global__ __launch_bounds__(256, 3) void k_ff2td_attn(
    const short* __restrict__ halltd, const short* __restrict__ W2td,
    const float* __restrict__ tdb2, const float* __restrict__ lv,
    const float* __restrict__ tokens, float* __restrict__ accum,
    const short* __restrict__ Apk, const float* __restrict__ invn,
    float* __restrict__ attnb)
{
  __shared__ __align__(16) char smem[34304];
  if (blockIdx.x < 640) {
    int bid = blockIdx.x;
    int gid = (bid & 7) * 80 + (bid >> 3);
    ff2_body(smem, halltd, W2td, tdb2, lv, tokens, accum, 0, 1, gid);
  } else {
    attn_body(smem, lv, Apk, invn, attnb, blockIdx.x - 640);
  }
}

// ---------------------------------------------------------------------------
// Consensus: accum += attnb @ lv (pure RMW). Grid 768, XCD-grouped by bl.
// ---------------------------------------------------------------------------
__global__ __launch_bounds__(256) void cons_k(
    const float* __restrict__ attnb, const float* __restrict__ lv,
    float* __restrict__ accum)
{
  __shared__ __align__(16) char smemraw[25088];
  const int a = blockIdx.x;
  const int s = a >> 3;
  const int bl = (a & 7) * 6 + (s >> 4);
  const int tile = s & 15;
  int it0 = (tile >> 2) * 64;
  int dt0 = (tile & 3) * 128;
  const float* A = attnb + (size_t)bl * 65536;
  const float* Bm = lv + (size_t)bl * 131072;
  float (*Ast)[68] = (float(*)[68])smemraw;
  float (*Bs)[128] = (float(*)[128])(smemraw + 8704);
  const int tid = threadIdx.x;
  const int ty = tid >> 4, tx = tid & 15;
  float acc[4][8];
#pragma unroll
  for (int i = 0; i < 4; ++i)
#pragma unroll
    for (int j = 0; j < 8; ++j) acc[i][j] = 0.f;

  for (int k0 = 0; k0 < 256; k0 += 32) {
#pragma unroll
    for (int it = 0; it < 2; ++it) {
      int f = it * 256 + tid;
      int r = f >> 3, c4 = f & 7;
      float4 v = *(const float4*)(A + (size_t)(it0 + r) * 256 + k0 + c4 * 4);
      Ast[c4 * 4 + 0][r] = v.x;
      Ast[c4 * 4 + 1][r] = v.y;
      Ast[c4 * 4 + 2][r] = v.z;
      Ast[c4 * 4 + 3][r] = v.w;
    }
#pragma unroll
    for (int it = 0; it < 4; ++it) {
      int kr = (tid >> 5) + it * 8;
      int c4 = tid & 31;
      *(float4*)&Bs[kr][c4 * 4] =
          *(const float4*)(Bm + (size_t)(k0 + kr) * 512 + dt0 + c4 * 4);
    }
    __syncthreads();
#pragma unroll 8
    for (int k = 0; k < 32; ++k) {
      float4 av = *(const float4*)&Ast[k][ty * 4];
      float4 b0 = *(const float4*)&Bs[k][tx * 4];
      float4 b1 = *(const float4*)&Bs[k][64 + tx * 4];
      float avv[4] = {av.x, av.y, av.z, av.w};
      float bv[8] = {b0.x, b0.y, b0.z, b0.w, b1.x, b1.y, b1.z, b1.w};
#pragma unroll
      for (int i = 0; i < 4; ++i)
#pragma unroll
        for (int j = 0; j < 8; ++j)
          acc[i][j] = fmaf(avv[i], bv[j], acc[i][j]);
    }
    __syncthreads();
  }
#pragma unroll
  for (int ii = 0; ii < 4; ++ii) {
    int i = it0 + ty * 4 + ii;
    float* arow = accum + (size_t)bl * 131072 + (size_t)i * 512 + dt0;
#pragma unroll
    for (int j = 0; j < 4; ++j) arow[tx * 4 + j] += acc[ii][j];
#pragma unroll
    for (int j = 0; j < 4; ++j) arow[64 + tx * 4 + j] += acc[ii][4 + j];
  }
}

// ---------------------------------------------------------------------------
// combine3: lv = accum/contrib, write dout on last iter, fused next-iter
// A-packing, and fused exact-fp32 row-norm via 64-lane butterfly.
// ---------------------------------------------------------------------------
__global__ __launch_bounds__(256) void combine3(
    const float* __restrict__ accum, const float* __restrict__ pos,
    float* __restrict__ lv_out, short* __restrict__ Abu,
    short* __restrict__ Atd, float* __restrict__ invn,
    float* __restrict__ dout, int last)
{
  int t = blockIdx.x * 256 + threadIdx.x;   // 786,432 total
  int d8 = t & 63;
  int n = (t >> 6) & 255;
  int v = t >> 14;                          // b*6 + l, 0..47
  int l = v % 6, b = v / 6;
  int bn = (b << 8) | n;
  size_t idx = ((size_t)v * 256 + n) * 512 + d8 * 8;
  float4 a0 = *(const float4*)(accum + idx);
  float4 a1 = *(const float4*)(accum + idx + 4);
  float sc = (l == 5) ? (1.0f / 3.0f) : 0.25f;
  float r[8];
  r[0] = a0.x * sc; r[1] = a0.y * sc; r[2] = a0.z * sc; r[3] = a0.w * sc;
  r[4] = a1.x * sc; r[5] = a1.y * sc; r[6] = a1.z * sc; r[7] = a1.w * sc;
  *(float4*)(lv_out + idx) = make_float4(r[0], r[1], r[2], r[3]);
  *(float4*)(lv_out + idx + 4) = make_float4(r[4], r[5], r[6], r[7]);
  if (last) {
    float* dp = dout + ((size_t)bn * 6 + l) * 512 + d8 * 8;
    *(float4*)dp = make_float4(r[0], r[1], r[2], r[3]);
    *(float4*)(dp + 4) = make_float4(r[4], r[5], r[6], r[7]);
  }
  // fused row norm: wave == one (v,n) row (d8 = lane)
  {
    float s8 = 0.f;
#pragma unroll
    for (int j = 0; j < 8; ++j) s8 = fmaf(r[j], r[j], s8);
#pragma unroll
    for (int o = 1; o < 64; o <<= 1) s8 += __shfl_xor(s8, o);
    if (d8 == 0) invn[(size_t)v * 256 + n] = 1.0f / fmaxf(sqrtf(s8), 1e-12f);
  }
  int m = bn;
  int mt = m >> 7;
  int kt = d8 >> 2;
  int s = (((m & 127) >> 4) << 6) | (((d8 & 3) << 4) | (m & 15));
  unsigned short hi[8], lo[8];
  if (l < 5) {
    size_t blk = ((size_t)(l * 16 + mt) * 16 + kt) * 8192;
#pragma unroll
    for (int j = 0; j < 8; ++j) split2(r[j], &hi[j], &lo[j]);
    *(int4*)(Abu + blk + s * 8) = pack8(hi);
    *(int4*)(Abu + blk + 4096 + s * 8) = pack8(lo);
  }
  if (l >= 1) {
    const float* pp = pos + (size_t)n * 512 + d8 * 8;
    float4 p0 = *(const float4*)pp;
    float4 p1 = *(const float4*)(pp + 4);
    float y[8] = {r[0] + p0.x, r[1] + p0.y, r[2] + p0.z, r[3] + p0.w,
                  r[4] + p1.x, r[5] + p1.y, r[6] + p1.z, r[7] + p1.w};
    size_t blk = ((size_t)((l - 1) * 16 + mt) * 16 + kt) * 8192;
#pragma unroll
    for (int j = 0; j < 8; ++j) split2(y[j], &hi[j], &lo[j]);
    *(int4*)(Atd + blk + s * 8) = pack8(hi);
    *(int4*)(Atd + blk + 4096 + s * 8) = pack8(lo);
  }
}

// ---------------------------------------------------------------------------
extern "C" void kernel_launch(void* const* d_in, const int* in_sizes, int n_in,
                              void* d_out, int out_size, void* d_ws, size_t ws_size,
                              hipStream_t stream)
{
  const float* img   = (const float*)d_in[0];
  const float* Wp    = (const float*)d_in[1];
  const float* bp    = (const float*)d_in[2];
  const float* pos   = (const float*)d_in[3];
  const float* initl = (const float*)d_in[4];
  const float* buW1  = (const float*)d_in[5];
  const float* bub1  = (const float*)d_in[6];
  const float* buW2  = (const float*)d_in[7];
  const float* bub2  = (const float*)d_in[8];
  const float* tdW1  = (const float*)d_in[9];
  const float* tdb1  = (const float*)d_in[10];
  const float* tdW2  = (const float*)d_in[11];
  const float* tdb2  = (const float*)d_in[12];

  float* ws = (float*)d_ws;
  const size_t LV = (size_t)8 * 6 * 256 * 512;   // 6,291,456 floats
  float* lv     = ws;
  float* tokens = lv + LV;                        // 1,048,576
  float* accum  = tokens + 1048576ull;            // 6,291,456
  short* W1all  = (short*)(accum + LV);           // 20,971,520 shorts
  short* W2all  = W1all + 20971520ull;            // 20,971,520 shorts
  short* Apk    = W2all + 20971520ull;            // 20,971,520 shorts
  short* hallbu = Apk + 20971520ull;              // 20,971,520 shorts (hi only)
  short* halltd = hallbu + 20971520ull;           // 20,971,520 shorts (hi only)
  float* invn   = (float*)(halltd + 20971520ull); // 48*256 f32 = 49,152 B
  // total = 54,525,952 + 5*41,943,040 + 49,152 = 264,290,304 B == capacity

  // attnb aliases hallbu (12.6 MB needed <= 41.9 MB): hallbu is consumed by
  // D2's ff2-bu; attn (D3) writes attnb over it; cons (D4) reads it; next
  // iter's D1 rewrites hallbu after D5 — all stream-ordered.
  float* attnb = (float*)hallbu;
  float* dout  = (float*)d_out;

  pack_w<<<2560, 256, 0, stream>>>(buW1, W1all, 16, 16);
  pack_w<<<2560, 256, 0, stream>>>(tdW1, W1all + 5 * SH_W_GRP, 16, 16);
  pack_w<<<2560, 256, 0, stream>>>(buW2, W2all, 64, 4);
  pack_w<<<2560, 256, 0, stream>>>(tdW2, W2all + 5 * SH_W_GRP, 64, 4);

  patch_embed<<<2048, 256, 0, stream>>>(img, Wp, bp, tokens);
  init_lv_kernel<<<6144, 256, 0, stream>>>(initl, lv);
  norm0_k<<<48, 256, 0, stream>>>(lv, invn);
  pack_A<<<1280, 256, 0, stream>>>(lv, pos, Apk, Apk + SH_A_TDOFF);

  for (int it = 0; it < 12; ++it) {
    // D1: ff1-bu -> hallbu
    ff1_k<<<1280, 256, 0, stream>>>(W1all, Apk, bub1, hallbu);
    // D2: ff2-bu (reads hallbu, accum=lv+v levels 1..5) || ff1-td -> halltd
    k_ff2bu_ff1td<<<1920, 256, 0, stream>>>(
        hallbu, W2all, bub2, lv, tokens, accum,
        W1all + 5 * SH_W_GRP, Apk + SH_A_TDOFF, tdb1, halltd);
    // D3: ff2-td (reads halltd; l0 store, l1-4 RMW) || attn -> attnb
    k_ff2td_attn<<<1024, 256, 0, stream>>>(
        halltd, W2all + 5 * SH_W_GRP, tdb2, lv, tokens, accum,
        Apk, invn, attnb);
    // D4: consensus RMW into accum
    cons_k<<<768, 256, 0, stream>>>(attnb, lv, accum);
    // D5: combine + dout + next-iter A-pack + fused norms
    combine3<<<3072, 256, 0, stream>>>(accum, pos, lv, Apk, Apk + SH_A_TDOFF,
                                       invn, dout, it == 11 ? 1 : 0);
  }
}

// Round 14
// 3870.005 us; speedup vs baseline: 1.3803x; 1.0117x over previous
//
#include <hip/hip_runtime.h>
#include <math.h>

// Problem constants: B=8, S=224, P=14, D=512, L=6, NPS=16, N=256, G=5, H=2048, iters=12
#define L6 6

typedef __attribute__((ext_vector_type(8))) short bf16x8;   // 8 bf16 in 4 VGPRs
typedef __attribute__((ext_vector_type(4))) float f32x4;    // MFMA accum

#define SH_W_GRP   2097152ull   // 512*2048 hi/lo bf16 (both W1 and W2)
#define SH_A_TDOFF 10485760ull  // Atd offset inside Apk (5 groups)

// Exact gelu (erff): r10-proven epilogue.
__device__ __forceinline__ float gelu_exact(float x) {
  return 0.5f * x * (1.0f + erff(x * 0.70710678118654752f));
}

__device__ __forceinline__ unsigned short bf16_rn(float x) {
  unsigned u = __float_as_uint(x);
  unsigned r = u + 0x7FFFu + ((u >> 16) & 1u);
  return (unsigned short)(r >> 16);
}
__device__ __forceinline__ float bf16_f(unsigned short h) {
  return __uint_as_float(((unsigned)h) << 16);
}
__device__ __forceinline__ void split2(float x, unsigned short* h, unsigned short* l) {
  unsigned short hh = bf16_rn(x);
  *h = hh;
  *l = bf16_rn(x - bf16_f(hh));
}
__device__ __forceinline__ int4 pack8(const unsigned short* v) {
  return make_int4((int)((unsigned)v[0] | ((unsigned)v[1] << 16)),
                   (int)((unsigned)v[2] | ((unsigned)v[3] << 16)),
                   (int)((unsigned)v[4] | ((unsigned)v[5] << 16)),
                   (int)((unsigned)v[6] | ((unsigned)v[7] << 16)));
}

__device__ __forceinline__ void gload16(const void* g, void* l) {
  __builtin_amdgcn_global_load_lds(
      (const __attribute__((address_space(1))) void*)g,
      (__attribute__((address_space(3))) void*)l, 16, 0, 0);
}

// ---------------------------------------------------------------------------
// Patch embedding body r14: 8 patches per block (grid 256). Each Wp float4
// is amortized over 8 patches (32 FMA/load, LDS-broadcast xs reads) — Wp L2
// traffic 2.4GB -> 300MB (r13's 1-patch/block version was L2-BW-bound at
// 127us: occ 91%, VALU 16%, HBM 1.6%). Per-output accumulation order is
// identical to r13 (k-ascending per half; half0+half1+bias) -> bit-identical.
// smem: xs[8][588] @0 (18816B), part[128][8][4] @18816 (16384B) = 35200B.
// ---------------------------------------------------------------------------
__device__ __forceinline__ void patch_embed_body(
    char* smem, const float* __restrict__ img, const float* __restrict__ Wp,
    const float* __restrict__ bp, float* __restrict__ tokens, int bn8)
{
  float (*xs)[588] = (float(*)[588])smem;
  float (*part)[8][4] = (float(*)[8][4])(smem + 18816);
  const int tid = threadIdx.x;
  for (int e = tid; e < 4704; e += 256) {
    int p = e / 588, k = e - p * 588;
    int m = bn8 * 8 + p;
    int b = m >> 8, n = m & 255;
    int i = n >> 4, j = n & 15;
    int c = k % 3;
    int t = k / 3;
    int pc = t % 14;
    int pr = t / 14;
    xs[p][k] = img[(((size_t)(b * 3 + c) * 224) + (i * 14 + pr)) * 224 + (j * 14 + pc)];
  }
  __syncthreads();
  const int kh = tid >> 7, dq = tid & 127, d0 = dq * 4;
  float acc[8][4];
#pragma unroll
  for (int p = 0; p < 8; ++p)
#pragma unroll
    for (int i = 0; i < 4; ++i) acc[p][i] = 0.f;
  const int kbeg = kh * 294;
  for (int k = kbeg; k < kbeg + 294; ++k) {
    float4 wv = *(const float4*)(Wp + (size_t)k * 512 + d0);
#pragma unroll
    for (int p = 0; p < 8; ++p) {
      float x = xs[p][k];
      acc[p][0] = fmaf(x, wv.x, acc[p][0]);
      acc[p][1] = fmaf(x, wv.y, acc[p][1]);
      acc[p][2] = fmaf(x, wv.z, acc[p][2]);
      acc[p][3] = fmaf(x, wv.w, acc[p][3]);
    }
  }
  if (kh == 0) {
#pragma unroll
    for (int p = 0; p < 8; ++p)
      *(float4*)&part[dq][p][0] =
          make_float4(acc[p][0], acc[p][1], acc[p][2], acc[p][3]);
  }
  __syncthreads();
  if (kh == 1) {
    float4 bv = *(const float4*)(bp + d0);
#pragma unroll
    for (int p = 0; p < 8; ++p) {
      int m = bn8 * 8 + p;
      float4 o = make_float4(part[dq][p][0] + acc[p][0] + bv.x,
                             part[dq][p][1] + acc[p][1] + bv.y,
                             part[dq][p][2] + acc[p][2] + bv.z,
                             part[dq][p][3] + acc[p][3] + bv.w);
      *(float4*)(tokens + (size_t)m * 512 + d0) = o;
    }
  }
}

// ---------------------------------------------------------------------------
__device__ __forceinline__ void init_lv_body(
    const float* __restrict__ initl, float* __restrict__ lv, int bidx)
{
  int f = bidx * 256 + threadIdx.x;
  int d4 = f & 127;
  int l = (f >> 15) % 6;
  float4 v = *(const float4*)(initl + (size_t)l * 512 + d4 * 4);
  *(float4*)(lv + (size_t)f * 4) = v;
}

// ---------------------------------------------------------------------------
__device__ __forceinline__ void pack_w_body(
    const float* __restrict__ src, short* __restrict__ dst, int KT, int NT,
    int inner)
{
  int sidx = inner * 256 + threadIdx.x;
  int slot = sidx & 511;
  int blk = sidx >> 9;
  int kt = blk % KT;
  int rest = blk / KT;
  int nt = rest % NT;
  int g = rest / NT;
  int f = slot >> 6, lane = slot & 63;
  int N = NT * 128, K = KT * 32;
  int n = nt * 128 + f * 16 + (lane & 15);
  int k0 = kt * 32 + (lane >> 4) * 8;
  const float* s = src + ((size_t)g * K + k0) * N + n;
  unsigned short hi[8], lo[8];
#pragma unroll
  for (int j = 0; j < 8; ++j) split2(s[(size_t)j * N], &hi[j], &lo[j]);
  short* d = dst + (size_t)blk * 8192 + slot * 8;
  *(int4*)d = pack8(hi);
  *(int4*)(d + 4096) = pack8(lo);
}

// ---------------------------------------------------------------------------
// Startup S1 r14: pack_w x4 (0..10239) || patch_embed (10240..10495) ||
// init_lv (10496..16639). All mutually independent. Bodies bit-identical
// to their serial versions.
// ---------------------------------------------------------------------------
__global__ __launch_bounds__(256) void startup1(
    const float* __restrict__ buW1, const float* __restrict__ tdW1,
    const float* __restrict__ buW2, const float* __restrict__ tdW2,
    short* __restrict__ W1all, short* __restrict__ W2all,
    const float* __restrict__ img, const float* __restrict__ Wp,
    const float* __restrict__ bp, float* __restrict__ tokens,
    const float* __restrict__ initl, float* __restrict__ lv)
{
  __shared__ __align__(16) char smem[35200];
  const int bx = blockIdx.x;
  if (bx < 10240) {
    int q = bx / 2560;
    int inner = bx - q * 2560;
    const float* src = (q == 0) ? buW1 : (q == 1) ? tdW1 : (q == 2) ? buW2 : tdW2;
    short* dst = (q == 0) ? W1all
               : (q == 1) ? W1all + 5 * SH_W_GRP
               : (q == 2) ? W2all
                          : W2all + 5 * SH_W_GRP;
    int KT = (q < 2) ? 16 : 64;
    int NT = (q < 2) ? 16 : 4;
    pack_w_body(src, dst, KT, NT, inner);
  } else if (bx < 10496) {
    patch_embed_body(smem, img, Wp, bp, tokens, bx - 10240);
  } else {
    init_lv_body(initl, lv, bx - 10496);
  }
}

// ---------------------------------------------------------------------------
// Startup S2 r14: norm0 (0..47) || pack_A (48..1327); both read lv from S1.
// ---------------------------------------------------------------------------
__global__ __launch_bounds__(256) void startup2(
    const float* __restrict__ lv, float* __restrict__ invn,
    const float* __restrict__ pos, short* __restrict__ Abu,
    short* __restrict__ Atd)
{
  if (blockIdx.x < 48) {
    int bl = blockIdx.x;
    int n = threadIdx.x;
    const float* row = lv + ((size_t)bl * 256 + n) * 512;
    float ss = 0.f;
    for (int k = 0; k < 512; k += 4) {
      float4 v = *(const float4*)(row + k);
      ss = fmaf(v.x, v.x, ss);
      ss = fmaf(v.y, v.y, ss);
      ss = fmaf(v.z, v.z, ss);
      ss = fmaf(v.w, v.w, ss);
    }
    invn[(size_t)bl * 256 + n] = 1.0f / fmaxf(sqrtf(ss), 1e-12f);
    return;
  }
  const int bx = blockIdx.x - 48;         // 0..1279
  const int lg = bx >> 8, mt = (bx >> 4) & 15, kt = bx & 15;
  const size_t blk = (size_t)bx * 8192;
#pragma unroll
  for (int ss = 0; ss < 2; ++ss) {
    int s = threadIdx.x + ss * 256;
    int f = s >> 6, l = s & 63;
    int m = mt * 128 + (f << 4) + (l & 15);
    int b = m >> 8, n = m & 255;
    int d = kt * 32 + ((l >> 4) << 3);
    const float* pbu = lv + ((size_t)(b * L6 + lg) * 256 + n) * 512 + d;
    const float* ptd = lv + ((size_t)(b * L6 + lg + 1) * 256 + n) * 512 + d;
    const float* pp = pos + (size_t)n * 512 + d;
    float4 u0 = *(const float4*)pbu;
    float4 u1 = *(const float4*)(pbu + 4);
    float xv[8] = {u0.x, u0.y, u0.z, u0.w, u1.x, u1.y, u1.z, u1.w};
    unsigned short hi[8], lo[8];
#pragma unroll
    for (int j = 0; j < 8; ++j) split2(xv[j], &hi[j], &lo[j]);
    *(int4*)(Abu + blk + s * 8) = pack8(hi);
    *(int4*)(Abu + blk + 4096 + s * 8) = pack8(lo);
    float4 v0 = *(const float4*)ptd;
    float4 v1 = *(const float4*)(ptd + 4);
    float4 p0 = *(const float4*)pp;
    float4 p1 = *(const float4*)(pp + 4);
    float yv[8] = {v0.x + p0.x, v0.y + p0.y, v0.z + p0.z, v0.w + p0.w,
                   v1.x + p1.x, v1.y + p1.y, v1.z + p1.z, v1.w + p1.w};
#pragma unroll
    for (int j = 0; j < 8; ++j) split2(yv[j], &hi[j], &lo[j]);
    *(int4*)(Atd + blk + s * 8) = pack8(hi);
    *(int4*)(Atd + blk + 4096 + s * 8) = pack8(lo);
  }
}

// ---------------------------------------------------------------------------
// FF1 body: flat GEMM 64x64 wave tiles, single-bf16 h out (r12-proven).
// ---------------------------------------------------------------------------
__device__ __forceinline__ void ff1_body(
    const short* __restrict__ Wa, const short* __restrict__ Ap,
    const float* __restrict__ b1, short* __restrict__ hpk, int gid)
{
  const int tt = gid & 15;
  const int tile = gid >> 4;
  const int ht = tile & 15;
  const int z = tile >> 4;
  const int tid = threadIdx.x, lane = tid & 63, w = tid >> 6;
  const int wm = (w >> 1) * 64, wn = (w & 1) * 64;
  const short* ga = Wa + (size_t)(z * 16 + ht) * 16 * 8192 + (wm << 5) + lane * 8;
  const short* gb = Ap + (size_t)(z * 16 + tt) * 16 * 8192 + (wn << 5) + lane * 8;

  f32x4 acc[4][4];
#pragma unroll
  for (int i = 0; i < 4; ++i)
#pragma unroll
    for (int j = 0; j < 4; ++j) acc[i][j] = (f32x4)(0.0f);

  for (int kt = 0; kt < 16; ++kt) {
    const short* pa = ga + (size_t)kt * 8192;
    const short* pb = gb + (size_t)kt * 8192;
    bf16x8 ah[4], al[4], bh[4], bl[4];
#pragma unroll
    for (int i = 0; i < 4; ++i) {
      ah[i] = *(const bf16x8*)(pa + i * 512);
      al[i] = *(const bf16x8*)(pa + 4096 + i * 512);
    }
#pragma unroll
    for (int j = 0; j < 4; ++j) {
      bh[j] = *(const bf16x8*)(pb + j * 512);
      bl[j] = *(const bf16x8*)(pb + 4096 + j * 512);
    }
#pragma unroll
    for (int j = 0; j < 4; ++j)
#pragma unroll
      for (int i = 0; i < 4; ++i)
        acc[i][j] = __builtin_amdgcn_mfma_f32_16x16x32_bf16(
            ah[i], bh[j], acc[i][j], 0, 0, 0);
#pragma unroll
    for (int j = 0; j < 4; ++j)
#pragma unroll
      for (int i = 0; i < 4; ++i)
        acc[i][j] = __builtin_amdgcn_mfma_f32_16x16x32_bf16(
            al[i], bh[j], acc[i][j], 0, 0, 0);
#pragma unroll
    for (int j = 0; j < 4; ++j)
#pragma unroll
      for (int i = 0; i < 4; ++i)
        acc[i][j] = __builtin_amdgcn_mfma_f32_16x16x32_bf16(
            ah[i], bl[j], acc[i][j], 0, 0, 0);
  }

  const int q = lane >> 4, t = lane & 15;
  const float* b1g = b1 + (size_t)z * 2048;
#pragma unroll
  for (int i = 0; i < 4; ++i) {
    int Hb = ht * 128 + wm + i * 16 + q * 4;
    float4 bv = *(const float4*)(b1g + Hb);
    float bb[4] = {bv.x, bv.y, bv.z, bv.w};
    int kt2 = Hb >> 5;
    int g2 = (Hb >> 3) & 3;
    int jb = Hb & 7;                       // 0 or 4
    size_t blkbase = ((size_t)(z * 16 + tt) * 64 + kt2) * 4096;
#pragma unroll
    for (int j = 0; j < 4; ++j) {
      int f2 = (wn >> 4) + j;
      size_t off = blkbase + (size_t)(f2 * 64 + g2 * 16 + t) * 8 + jb;
      unsigned short hi[4];
#pragma unroll
      for (int r = 0; r < 4; ++r)
        hi[r] = bf16_rn(gelu_exact(acc[i][j][r] + bb[r]));
      *(uint2*)(hpk + off) =
          make_uint2((unsigned)hi[0] | ((unsigned)hi[1] << 16),
                     (unsigned)hi[2] | ((unsigned)hi[3] << 16));
    }
  }
}

// ---------------------------------------------------------------------------
// FF2 body: LDS-staged, single-bf16 h in, hi/lo W2 (r12-proven).
// smem layout: SA short[2048] @0, SB short[8192] @4096B (20480 B total).
// ---------------------------------------------------------------------------
__device__ __forceinline__ void ff2_body(
    char* smem, const short* __restrict__ hpk, const short* __restrict__ Wb,
    const float* __restrict__ b2, const float* __restrict__ lv,
    const float* __restrict__ tokens, float* __restrict__ accum,
    int olvbase, int emode, int gid)
{
  short* SA = (short*)smem;
  short* SB = (short*)(smem + 4096);
  const int nt2 = gid & 3;
  const int tile = gid >> 2;
  const int mt2 = tile & 31;          // 64-token tiles
  const int z = tile >> 5;

  const int tid = threadIdx.x, lane = tid & 63, w = tid >> 6;
  const int wm = (w >> 1) * 32, wn = (w & 1) * 64;
  const short* gaBase = hpk + (size_t)(z * 16 + (mt2 >> 1)) * 64 * 4096
                        + (size_t)(mt2 & 1) * 2048;
  const short* gb = Wb + (size_t)(z * 4 + nt2) * 64 * 8192;

  f32x4 acc[2][4];
#pragma unroll
  for (int i = 0; i < 2; ++i)
#pragma unroll
    for (int j = 0; j < 4; ++j) acc[i][j] = (f32x4)(0.0f);

  for (int kt = 0; kt < 64; ++kt) {
    __syncthreads();
    const char* pa = (const char*)(gaBase + (size_t)kt * 4096);
    const char* pb = (const char*)(gb + (size_t)kt * 8192);
    gload16(pa + w * 1024 + lane * 16, (char*)SA + w * 1024);
#pragma unroll
    for (int c = 0; c < 4; ++c)
      gload16(pb + w * 4096 + c * 1024 + lane * 16,
              (char*)SB + w * 4096 + c * 1024);
    __syncthreads();
    bf16x8 ah[2];
#pragma unroll
    for (int i = 0; i < 2; ++i) {
      int f = (wm >> 4) + i;
      ah[i] = *(const bf16x8*)&SA[f * 512 + lane * 8];
    }
#pragma unroll
    for (int jp = 0; jp < 2; ++jp) {
      bf16x8 bh[2], bl[2];
#pragma unroll
      for (int j2 = 0; j2 < 2; ++j2) {
        int f = (wn >> 4) + jp * 2 + j2;
        bh[j2] = *(const bf16x8*)&SB[f * 512 + lane * 8];
        bl[j2] = *(const bf16x8*)&SB[4096 + f * 512 + lane * 8];
      }
#pragma unroll
      for (int j2 = 0; j2 < 2; ++j2)
#pragma unroll
        for (int i = 0; i < 2; ++i)
          acc[i][jp * 2 + j2] = __builtin_amdgcn_mfma_f32_16x16x32_bf16(
              ah[i], bh[j2], acc[i][jp * 2 + j2], 0, 0, 0);
#pragma unroll
      for (int j2 = 0; j2 < 2; ++j2)
#pragma unroll
        for (int i = 0; i < 2; ++i)
          acc[i][jp * 2 + j2] = __builtin_amdgcn_mfma_f32_16x16x32_bf16(
              ah[i], bl[j2], acc[i][jp * 2 + j2], 0, 0, 0);
    }
  }

  const int q = lane >> 4, t = lane & 15;
  const float* b2g = b2 + (size_t)z * 512;
  const int level = olvbase + z;
#pragma unroll
  for (int i = 0; i < 2; ++i) {
#pragma unroll
    for (int r = 0; r < 4; ++r) {
      int m = mt2 * 64 + wm + i * 16 + q * 4 + r;
      int b = m >> 8, n = m & 255;
      size_t rowoff = ((size_t)(b * L6 + level) * 256 + n) * 512;
      float* arow = accum + rowoff;
      const float* lrow = lv + rowoff;
      const float* trow = tokens + (size_t)m * 512;
#pragma unroll
      for (int j = 0; j < 4; ++j) {
        int col = nt2 * 128 + wn + j * 16 + t;
        float v = acc[i][j][r] + b2g[col];
        if (emode == 0)                       arow[col] = lrow[col] + v;
        else if (level == 0)                  arow[col] = lrow[col] + trow[col] + v;
        else                                  arow[col] += v;
      }
    }
  }
}

// ---------------------------------------------------------------------------
// Attention body (r7-proven): MFMA Gram + norm table.
// smem: Bhi short[8192] @0, Blo short[8192] @16384, scL float[256] @32768,
// red float[32][4] @33792 (34304 B total).
// ---------------------------------------------------------------------------
__device__ __forceinline__ void attn_body(
    char* smem, const float* __restrict__ lv, const short* __restrict__ Apk,
    const float* __restrict__ invn, float* __restrict__ attnb, int a)
{
  short* Bhi = (short*)smem;
  short* Blo = (short*)(smem + 16384);
  float* scL = (float*)(smem + 32768);
  float (*red)[4] = (float(*)[4])(smem + 33792);
  const int s = a >> 3;
  const int b = a & 7;                 // batch == XCD group
  const int l = s >> 3;                // level 0..5
  const int bl = b * 6 + l;
  const int i0 = (s & 7) * 32;
  const float* base = lv + (size_t)bl * 131072;
  const int tid = threadIdx.x, lane = tid & 63, w = tid >> 6;
  const int q = lane >> 4, c = lane & 15;

  scL[tid] = invn[(size_t)bl * 256 + tid];

  f32x4 acc[2][4];
#pragma unroll
  for (int i = 0; i < 2; ++i)
#pragma unroll
    for (int j = 0; j < 4; ++j) acc[i][j] = (f32x4)(0.0f);

  const short* src0 = Apk + ((size_t)(l * 16 + 2 * b) * 16) * 8192;
  const short* src1 = Apk + ((size_t)(l * 16 + 2 * b + 1) * 16) * 8192;

  for (int kt = 0; kt < 16; ++kt) {
    __syncthreads();
    if (l < 5) {
      const char* p0 = (const char*)(src0 + (size_t)kt * 8192);
      const char* p1 = (const char*)(src1 + (size_t)kt * 8192);
      gload16(p0 + tid * 16,         (char*)Bhi + tid * 16);
      gload16(p0 + 4096 + tid * 16,  (char*)Bhi + 4096 + tid * 16);
      gload16(p0 + 8192 + tid * 16,  (char*)Blo + tid * 16);
      gload16(p0 + 12288 + tid * 16, (char*)Blo + 4096 + tid * 16);
      gload16(p1 + tid * 16,         (char*)Bhi + 8192 + tid * 16);
      gload16(p1 + 4096 + tid * 16,  (char*)Bhi + 12288 + tid * 16);
      gload16(p1 + 8192 + tid * 16,  (char*)Blo + 8192 + tid * 16);
      gload16(p1 + 12288 + tid * 16, (char*)Blo + 12288 + tid * 16);
    } else {
      const int k0 = kt * 32;
#pragma unroll
      for (int it = 0; it < 8; ++it) {
        int f = it * 256 + tid;
        int j = f >> 3, c4 = f & 7;
        float4 v = *(const float4*)(base + (size_t)j * 512 + k0 + c4 * 4);
        unsigned short hi[4], lo[4];
        split2(v.x, &hi[0], &lo[0]);
        split2(v.y, &hi[1], &lo[1]);
        split2(v.z, &hi[2], &lo[2]);
        split2(v.w, &hi[3], &lo[3]);
        int fg = j >> 4;
        int la = (c4 >> 1) * 16 + (j & 15);
        int half = (c4 & 1) * 4;
        *(uint2*)&Bhi[fg * 512 + la * 8 + half] =
            make_uint2((unsigned)hi[0] | ((unsigned)hi[1] << 16),
                       (unsigned)hi[2] | ((unsigned)hi[3] << 16));
        *(uint2*)&Blo[fg * 512 + la * 8 + half] =
            make_uint2((unsigned)lo[0] | ((unsigned)lo[1] << 16),
                       (unsigned)lo[2] | ((unsigned)lo[3] << 16));
      }
    }
    __syncthreads();
    bf16x8 ah[2], al[2], bh[4], blv[4];
#pragma unroll
    for (int i = 0; i < 2; ++i) {
      int fg = (i0 >> 4) + i;
      ah[i] = *(const bf16x8*)&Bhi[fg * 512 + lane * 8];
      al[i] = *(const bf16x8*)&Blo[fg * 512 + lane * 8];
    }
#pragma unroll
    for (int j = 0; j < 4; ++j) {
      int fg = w * 4 + j;
      bh[j] = *(const bf16x8*)&Bhi[fg * 512 + lane * 8];
      blv[j] = *(const bf16x8*)&Blo[fg * 512 + lane * 8];
    }
#pragma unroll
    for (int j = 0; j < 4; ++j)
#pragma unroll
      for (int i = 0; i < 2; ++i)
        acc[i][j] = __builtin_amdgcn_mfma_f32_16x16x32_bf16(
            ah[i], bh[j], acc[i][j], 0, 0, 0);
#pragma unroll
    for (int j = 0; j < 4; ++j)
#pragma unroll
      for (int i = 0; i < 2; ++i)
        acc[i][j] = __builtin_amdgcn_mfma_f32_16x16x32_bf16(
            al[i], bh[j], acc[i][j], 0, 0, 0);
#pragma unroll
    for (int j = 0; j < 4; ++j)
#pragma unroll
      for (int i = 0; i < 2; ++i)
        acc[i][j] = __builtin_amdgcn_mfma_f32_16x16x32_bf16(
            ah[i], blv[j], acc[i][j], 0, 0, 0);
  }
  __syncthreads();

  const float rs = 0.04419417382415922f;  // 512^-0.5
#pragma unroll
  for (int ai = 0; ai < 2; ++ai)
#pragma unroll
    for (int bj = 0; bj < 4; ++bj)
#pragma unroll
      for (int r = 0; r < 4; ++r) {
        int i = i0 + ai * 16 + q * 4 + r;
        int j = w * 64 + bj * 16 + c;
        float sv = acc[ai][bj][r] * scL[j] * rs;
        if (j == i) sv = -0.0005f;
        acc[ai][bj][r] = sv;
      }
  float mx[2][4];
#pragma unroll
  for (int ai = 0; ai < 2; ++ai)
#pragma unroll
    for (int r = 0; r < 4; ++r) {
      float m = fmaxf(fmaxf(acc[ai][0][r], acc[ai][1][r]),
                      fmaxf(acc[ai][2][r], acc[ai][3][r]));
      m = fmaxf(m, __shfl_xor(m, 1));
      m = fmaxf(m, __shfl_xor(m, 2));
      m = fmaxf(m, __shfl_xor(m, 4));
      m = fmaxf(m, __shfl_xor(m, 8));
      mx[ai][r] = m;
    }
  if (c == 0) {
#pragma unroll
    for (int ai = 0; ai < 2; ++ai)
#pragma unroll
      for (int r = 0; r < 4; ++r) red[ai * 16 + q * 4 + r][w] = mx[ai][r];
  }
  __syncthreads();
#pragma unroll
  for (int ai = 0; ai < 2; ++ai)
#pragma unroll
    for (int r = 0; r < 4; ++r) {
      int row = ai * 16 + q * 4 + r;
      mx[ai][r] = fmaxf(fmaxf(red[row][0], red[row][1]),
                        fmaxf(red[row][2], red[row][3]));
    }
  __syncthreads();
  float sm[2][4];
#pragma unroll
  for (int ai = 0; ai < 2; ++ai)
#pragma unroll
    for (int r = 0; r < 4; ++r) {
      float t = 0.f;
#pragma unroll
      for (int bj = 0; bj < 4; ++bj) {
        float e = expf(acc[ai][bj][r] - mx[ai][r]);
        acc[ai][bj][r] = e;
        t += e;
      }
      t += __shfl_xor(t, 1);
      t += __shfl_xor(t, 2);
      t += __shfl_xor(t, 4);
      t += __shfl_xor(t, 8);
      sm[ai][r] = t;
    }
  if (c == 0) {
#pragma unroll
    for (int ai = 0; ai < 2; ++ai)
#pragma unroll
      for (int r = 0; r < 4; ++r) red[ai * 16 + q * 4 + r][w] = sm[ai][r];
  }
  __syncthreads();
  float* ob = attnb + (size_t)bl * 65536;
#pragma unroll
  for (int ai = 0; ai < 2; ++ai)
#pragma unroll
    for (int r = 0; r < 4; ++r) {
      int row = ai * 16 + q * 4 + r;
      float S = red[row][0] + red[row][1] + red[row][2] + red[row][3];
      float inv = 1.0f / S;
      int i = i0 + row;
#pragma unroll
      for (int bj = 0; bj < 4; ++bj) {
        int j = w * 64 + bj * 16 + c;
        ob[(size_t)i * 256 + j] = acc[ai][bj][r] * inv;
      }
    }
}

// ---------------------------------------------------------------------------
// Standalone ff1 (D1: bu). Grid 1280.
// ---------------------------------------------------------------------------
__global__ __launch_bounds__(256, 3) void ff1_k(
    const short* __restrict__ Wa, const short* __restrict__ Ap,
    const float* __restrict__ b1, short* __restrict__ hpk)
{
  const int per_x = gridDim.x >> 3;
  const int gid = (blockIdx.x & 7) * per_x + (blockIdx.x >> 3);
  ff1_body(Wa, Ap, b1, hpk, gid);
}

// ---------------------------------------------------------------------------
// D2: ff2-bu (blocks 0..639) CO-DISPATCHED with ff1-td (640..1919).
// ---------------------------------------------------------------------------
__global__ __launch_bounds__(256, 3) void k_ff2bu_ff1td(
    const short* __restrict__ hallbu, const short* __restrict__ W2,
    const float* __restrict__ bub2, const float* __restrict__ lv,
    const float* __restrict__ tokens, float* __restrict__ accum,
    const short* __restrict__ W1td, const short* __restrict__ Atd,
    const float* __restrict__ tdb1, short* __restrict__ halltd)
{
  __shared__ __align__(16) char smem[20480];
  if (blockIdx.x < 640) {
    int bid = blockIdx.x;
    int gid = (bid & 7) * 80 + (bid >> 3);
    ff2_body(smem, hallbu, W2, bub2, lv, tokens, accum, 1, 0, gid);
  } else {
    int bid = blockIdx.x - 640;
    int gid = (bid & 7) * 160 + (bid >> 3);
    ff1_body(W1td, Atd, tdb1, halltd, gid);
  }
}

// ---------------------------------------------------------------------------
// D3: ff2-td (blocks 0..639) CO-DISPATCHED with attn (640..1023).
// ---------------------------------------------------------------------------
__global__ __launch_bounds__(256, 3) void k_ff2td_attn(
    const short* __restrict__ halltd, const short* __restrict__ W2td,
    const float* __restrict__ tdb2, const float* __restrict__ lv,
    const float* __restrict__ tokens, float* __restrict__ accum,
    const short* __restrict__ Apk, const float* __restrict__ invn,
    float* __restrict__ attnb)
{
  __shared__ __align__(16) char smem[34304];
  if (blockIdx.x < 640) {
    int bid = blockIdx.x;
    int gid = (bid & 7) * 80 + (bid >> 3);
    ff2_body(smem, halltd, W2td, tdb2, lv, tokens, accum, 0, 1, gid);
  } else {
    attn_body(smem, lv, Apk, invn, attnb, blockIdx.x - 640);
  }
}

// ---------------------------------------------------------------------------
// Consensus: accum += attnb @ lv (pure RMW). Grid 768, XCD-grouped by bl.
// ---------------------------------------------------------------------------
__global__ __launch_bounds__(256) void cons_k(
    const float* __restrict__ attnb, const float* __restrict__ lv,
    float* __restrict__ accum)
{
  __shared__ __align__(16) char smemraw[25088];
  const int a = blockIdx.x;
  const int s = a >> 3;
  const int bl = (a & 7) * 6 + (s >> 4);
  const int tile = s & 15;
  int it0 = (tile >> 2) * 64;
  int dt0 = (tile & 3) * 128;
  const float* A = attnb + (size_t)bl * 65536;
  const float* Bm = lv + (size_t)bl * 131072;
  float (*Ast)[68] = (float(*)[68])smemraw;
  float (*Bs)[128] = (float(*)[128])(smemraw + 8704);
  const int tid = threadIdx.x;
  const int ty = tid >> 4, tx = tid & 15;
  float acc[4][8];
#pragma unroll
  for (int i = 0; i < 4; ++i)
#pragma unroll
    for (int j = 0; j < 8; ++j) acc[i][j] = 0.f;

  for (int k0 = 0; k0 < 256; k0 += 32) {
#pragma unroll
    for (int it = 0; it < 2; ++it) {
      int f = it * 256 + tid;
      int r = f >> 3, c4 = f & 7;
      float4 v = *(const float4*)(A + (size_t)(it0 + r) * 256 + k0 + c4 * 4);
      Ast[c4 * 4 + 0][r] = v.x;
      Ast[c4 * 4 + 1][r] = v.y;
      Ast[c4 * 4 + 2][r] = v.z;
      Ast[c4 * 4 + 3][r] = v.w;
    }
#pragma unroll
    for (int it = 0; it < 4; ++it) {
      int kr = (tid >> 5) + it * 8;
      int c4 = tid & 31;
      *(float4*)&Bs[kr][c4 * 4] =
          *(const float4*)(Bm + (size_t)(k0 + kr) * 512 + dt0 + c4 * 4);
    }
    __syncthreads();
#pragma unroll 8
    for (int k = 0; k < 32; ++k) {
      float4 av = *(const float4*)&Ast[k][ty * 4];
      float4 b0 = *(const float4*)&Bs[k][tx * 4];
      float4 b1 = *(const float4*)&Bs[k][64 + tx * 4];
      float avv[4] = {av.x, av.y, av.z, av.w};
      float bv[8] = {b0.x, b0.y, b0.z, b0.w, b1.x, b1.y, b1.z, b1.w};
#pragma unroll
      for (int i = 0; i < 4; ++i)
#pragma unroll
        for (int j = 0; j < 8; ++j)
          acc[i][j] = fmaf(avv[i], bv[j], acc[i][j]);
    }
    __syncthreads();
  }
#pragma unroll
  for (int ii = 0; ii < 4; ++ii) {
    int i = it0 + ty * 4 + ii;
    float* arow = accum + (size_t)bl * 131072 + (size_t)i * 512 + dt0;
#pragma unroll
    for (int j = 0; j < 4; ++j) arow[tx * 4 + j] += acc[ii][j];
#pragma unroll
    for (int j = 0; j < 4; ++j) arow[64 + tx * 4 + j] += acc[ii][4 + j];
  }
}

// ---------------------------------------------------------------------------
// combine3: lv = accum/contrib, write dout on last iter, fused next-iter
// A-packing, and fused exact-fp32 row-norm via 64-lane butterfly.
// ---------------------------------------------------------------------------
__global__ __launch_bounds__(256) void combine3(
    const float* __restrict__ accum, const float* __restrict__ pos,
    float* __restrict__ lv_out, short* __restrict__ Abu,
    short* __restrict__ Atd, float* __restrict__ invn,
    float* __restrict__ dout, int last)
{
  int t = blockIdx.x * 256 + threadIdx.x;   // 786,432 total
  int d8 = t & 63;
  int n = (t >> 6) & 255;
  int v = t >> 14;                          // b*6 + l, 0..47
  int l = v % 6, b = v / 6;
  int bn = (b << 8) | n;
  size_t idx = ((size_t)v * 256 + n) * 512 + d8 * 8;
  float4 a0 = *(const float4*)(accum + idx);
  float4 a1 = *(const float4*)(accum + idx + 4);
  float sc = (l == 5) ? (1.0f / 3.0f) : 0.25f;
  float r[8];
  r[0] = a0.x * sc; r[1] = a0.y * sc; r[2] = a0.z * sc; r[3] = a0.w * sc;
  r[4] = a1.x * sc; r[5] = a1.y * sc; r[6] = a1.z * sc; r[7] = a1.w * sc;
  *(float4*)(lv_out + idx) = make_float4(r[0], r[1], r[2], r[3]);
  *(float4*)(lv_out + idx + 4) = make_float4(r[4], r[5], r[6], r[7]);
  if (last) {
    float* dp = dout + ((size_t)bn * 6 + l) * 512 + d8 * 8;
    *(float4*)dp = make_float4(r[0], r[1], r[2], r[3]);
    *(float4*)(dp + 4) = make_float4(r[4], r[5], r[6], r[7]);
  }
  // fused row norm: wave == one (v,n) row (d8 = lane)
  {
    float s8 = 0.f;
#pragma unroll
    for (int j = 0; j < 8; ++j) s8 = fmaf(r[j], r[j], s8);
#pragma unroll
    for (int o = 1; o < 64; o <<= 1) s8 += __shfl_xor(s8, o);
    if (d8 == 0) invn[(size_t)v * 256 + n] = 1.0f / fmaxf(sqrtf(s8), 1e-12f);
  }
  int m = bn;
  int mt = m >> 7;
  int kt = d8 >> 2;
  int s = (((m & 127) >> 4) << 6) | (((d8 & 3) << 4) | (m & 15));
  unsigned short hi[8], lo[8];
  if (l < 5) {
    size_t blk = ((size_t)(l * 16 + mt) * 16 + kt) * 8192;
#pragma unroll
    for (int j = 0; j < 8; ++j) split2(r[j], &hi[j], &lo[j]);
    *(int4*)(Abu + blk + s * 8) = pack8(hi);
    *(int4*)(Abu + blk + 4096 + s * 8) = pack8(lo);
  }
  if (l >= 1) {
    const float* pp = pos + (size_t)n * 512 + d8 * 8;
    float4 p0 = *(const float4*)pp;
    float4 p1 = *(const float4*)(pp + 4);
    float y[8] = {r[0] + p0.x, r[1] + p0.y, r[2] + p0.z, r[3] + p0.w,
                  r[4] + p1.x, r[5] + p1.y, r[6] + p1.z, r[7] + p1.w};
    size_t blk = ((size_t)((l - 1) * 16 + mt) * 16 + kt) * 8192;
#pragma unroll
    for (int j = 0; j < 8; ++j) split2(y[j], &hi[j], &lo[j]);
    *(int4*)(Atd + blk + s * 8) = pack8(hi);
    *(int4*)(Atd + blk + 4096 + s * 8) = pack8(lo);
  }
}

// ---------------------------------------------------------------------------
extern "C" void kernel_launch(void* const* d_in, const int* in_sizes, int n_in,
                              void* d_out, int out_size, void* d_ws, size_t ws_size,
                              hipStream_t stream)
{
  const float* img   = (const float*)d_in[0];
  const float* Wp    = (const float*)d_in[1];
  const float* bp    = (const float*)d_in[2];
  const float* pos   = (const float*)d_in[3];
  const float* initl = (const float*)d_in[4];
  const float* buW1  = (const float*)d_in[5];
  const float* bub1  = (const float*)d_in[6];
  const float* buW2  = (const float*)d_in[7];
  const float* bub2  = (const float*)d_in[8];
  const float* tdW1  = (const float*)d_in[9];
  const float* tdb1  = (const float*)d_in[10];
  const float* tdW2  = (const float*)d_in[11];
  const float* tdb2  = (const float*)d_in[12];

  float* ws = (float*)d_ws;
  const size_t LV = (size_t)8 * 6 * 256 * 512;   // 6,291,456 floats
  float* lv     = ws;
  float* tokens = lv + LV;                        // 1,048,576
  float* accum  = tokens + 1048576ull;            // 6,291,456
  short* W1all  = (short*)(accum + LV);           // 20,971,520 shorts
  short* W2all  = W1all + 20971520ull;            // 20,971,520 shorts
  short* Apk    = W2all + 20971520ull;            // 20,971,520 shorts
  short* hallbu = Apk + 20971520ull;              // 20,971,520 shorts (hi only)
  short* halltd = hallbu + 20971520ull;           // 20,971,520 shorts (hi only)
  float* invn   = (float*)(halltd + 20971520ull); // 48*256 f32 = 49,152 B
  // total = 54,525,952 + 5*41,943,040 + 49,152 = 264,290,304 B == capacity

  // attnb aliases hallbu (12.6 MB <= 41.9 MB): hallbu consumed by D2's
  // ff2-bu; attn (D3) overwrites it; cons (D4) reads it; next iter's D1
  // rewrites hallbu after D5 — all stream-ordered.
  float* attnb = (float*)hallbu;
  float* dout  = (float*)d_out;

  // S1: pack_w x4 || patch_embed || init_lv (all independent)
  startup1<<<16640, 256, 0, stream>>>(buW1, tdW1, buW2, tdW2, W1all, W2all,
                                      img, Wp, bp, tokens, initl, lv);
  // S2: norm0 || pack_A (both read lv)
  startup2<<<1328, 256, 0, stream>>>(lv, invn, pos, Apk, Apk + SH_A_TDOFF);

  for (int it = 0; it < 12; ++it) {
    // D1: ff1-bu -> hallbu
    ff1_k<<<1280, 256, 0, stream>>>(W1all, Apk, bub1, hallbu);
    // D2: ff2-bu (reads hallbu, accum=lv+v levels 1..5) || ff1-td -> halltd
    k_ff2bu_ff1td<<<1920, 256, 0, stream>>>(
        hallbu, W2all, bub2, lv, tokens, accum,
        W1all + 5 * SH_W_GRP, Apk + SH_A_TDOFF, tdb1, halltd);
    // D3: ff2-td (reads halltd; l0 store, l1-4 RMW) || attn -> attnb
    k_ff2td_attn<<<1024, 256, 0, stream>>>(
        halltd, W2all + 5 * SH_W_GRP, tdb2, lv, tokens, accum,
        Apk, invn, attnb);
    // D4: consensus RMW into accum
    cons_k<<<768, 256, 0, stream>>>(attnb, lv, accum);
    // D5: combine + dout + next-iter A-pack + fused norms
    combine3<<<3072, 256, 0, stream>>>(accum, pos, lv, Apk, Apk + SH_A_TDOFF,
                                       invn, dout, it == 11 ? 1 : 0);
  }
}